// Round 1
// baseline (1151.777 us; speedup 1.0000x reference)
//
#include <hip/hip_runtime.h>
#include <hip/hip_bf16.h>

constexpr int NNODES = 8192;

__device__ __forceinline__ float eluf(float z) {
  return z > 0.f ? z : __expf(z) - 1.f;
}

// ---------------------------------------------------------------------------
// GEMM: C[M][NOUT] = A[M][K] @ W[K][NOUT]   (fp32, BM=64,BN=64,BK=16, 4x4 micro)
// ---------------------------------------------------------------------------
template<int K, int NOUT>
__global__ __launch_bounds__(256) void gemm_kernel(
    const float* __restrict__ A, const float* __restrict__ W, float* __restrict__ C) {
  constexpr int BM = 64, BN = 64, BK = 16;
  __shared__ __align__(16) float As[BK][BM + 4];   // k-major (transposed store)
  __shared__ __align__(16) float Ws[BK][BN];
  const int t = threadIdx.x;
  const int i0 = blockIdx.x * BM;
  const int c0 = blockIdx.y * BN;
  const int tr = t >> 4;        // 0..15 -> rows 4tr..4tr+3
  const int tc = t & 15;        // 0..15 -> cols 4tc..4tc+3
  const int lr = t >> 2;        // A-load row 0..63
  const int lk = (t & 3) * 4;   // A-load k quad
  const int wk = t >> 4;        // W-load k 0..15
  const int wc = (t & 15) * 4;  // W-load col quad
  float acc[4][4] = {};
  for (int k0 = 0; k0 < K; k0 += BK) {
    const float4 a4 = *reinterpret_cast<const float4*>(&A[(size_t)(i0 + lr) * K + k0 + lk]);
    As[lk + 0][lr] = a4.x; As[lk + 1][lr] = a4.y;
    As[lk + 2][lr] = a4.z; As[lk + 3][lr] = a4.w;
    *reinterpret_cast<float4*>(&Ws[wk][wc]) =
        *reinterpret_cast<const float4*>(&W[(size_t)(k0 + wk) * NOUT + c0 + wc]);
    __syncthreads();
    #pragma unroll
    for (int kk = 0; kk < BK; ++kk) {
      const float4 av = *reinterpret_cast<const float4*>(&As[kk][4 * tr]);
      const float4 wv = *reinterpret_cast<const float4*>(&Ws[kk][4 * tc]);
      const float a[4] = {av.x, av.y, av.z, av.w};
      const float w[4] = {wv.x, wv.y, wv.z, wv.w};
      #pragma unroll
      for (int i = 0; i < 4; ++i)
        #pragma unroll
        for (int j = 0; j < 4; ++j) acc[i][j] += a[i] * w[j];
    }
    __syncthreads();
  }
  #pragma unroll
  for (int i = 0; i < 4; ++i) {
    const float4 o = make_float4(acc[i][0], acc[i][1], acc[i][2], acc[i][3]);
    *reinterpret_cast<float4*>(&C[(size_t)(i0 + 4 * tr + i) * NOUT + c0 + 4 * tc]) = o;
  }
}

// ---------------------------------------------------------------------------
// s[i] = h[i] . a_self ; n[i] = h[i] . a_neigh   (one wave per row)
// ---------------------------------------------------------------------------
template<int FOUT>
__global__ __launch_bounds__(256) void sn_kernel(
    const float* __restrict__ H, const float* __restrict__ a_self,
    const float* __restrict__ a_neigh, float* __restrict__ s, float* __restrict__ n) {
  const int wave = threadIdx.x >> 6;
  const int lane = threadIdx.x & 63;
  const int row = blockIdx.x * 4 + wave;
  float ds = 0.f, dn = 0.f;
  #pragma unroll
  for (int c = lane; c < FOUT; c += 64) {
    const float h = H[(size_t)row * FOUT + c];
    ds += h * a_self[c];
    dn += h * a_neigh[c];
  }
  #pragma unroll
  for (int off = 32; off > 0; off >>= 1) {
    ds += __shfl_down(ds, off);
    dn += __shfl_down(dn, off);
  }
  if (lane == 0) { s[row] = ds; n[row] = dn; }
}

// ---------------------------------------------------------------------------
// Fused masked-softmax attention + PV + elu.
// BR=32 rows/block, BC=32 cols/tile, 512 threads (8 waves).
// p_ij = adj ? exp(min(lrelu((s_i+n_j)*M_ij), 70)) : 0  (fixed max=0; exact
// softmax since scores are data-bounded << 70).  out = elu((P@H) / rowsum(P)).
// ---------------------------------------------------------------------------
template<int FOUT>
__global__ __launch_bounds__(512) void attn_kernel(
    const float* __restrict__ Mm, const int* __restrict__ adj,
    const float* __restrict__ sv, const float* __restrict__ nv,
    const float* __restrict__ H, float* __restrict__ out) {
  constexpr int BR = 32, BC = 32;
  constexpr int NT = NNODES / BC;
  constexpr int VEC = (FOUT == 256) ? 4 : 2;
  constexpr int NCH = FOUT / (32 * VEC);   // 256 -> 2, 64 -> 1
  __shared__ __align__(16) float P[BR][BC];
  __shared__ __align__(16) float Hs[BC * FOUT];
  __shared__ float s_lds[BR];
  __shared__ float l_lds[BR];

  const int t = threadIdx.x;
  const int i0 = blockIdx.x * BR;
  const int c = t & 31;        // score col / PV col-group
  const int rb = t >> 5;       // 0..15: score rows rb, rb+16; PV rows 2rb, 2rb+1
  const int wv_ = t >> 6;      // wave id
  const int lane = t & 63;

  if (t < BR) { s_lds[t] = sv[i0 + t]; l_lds[t] = 0.f; }

  const size_t row0 = (size_t)(i0 + rb) * NNODES + c;
  const size_t row1 = row0 + (size_t)16 * NNODES;
  float mc0 = Mm[row0], mc1 = Mm[row1];
  int   ac0 = adj[row0], ac1 = adj[row1];
  float ncr = nv[c];

  float acc[2][NCH][VEC] = {};
  __syncthreads();

  for (int tj = 0; tj < NT; ++tj) {
    const int j0 = tj * BC;
    // ---- async stage H tile -> LDS (linear, wave-uniform dest + lane*16) ----
    {
      constexpr int NISS = (BC * FOUT) / (256 * 8);  // 1KB per wave-issue
      const float* srcb = H + (size_t)j0 * FOUT;
      #pragma unroll
      for (int q = 0; q < NISS; ++q) {
        const int foff = (wv_ * NISS + q) * 256;
        __builtin_amdgcn_global_load_lds(
            (__attribute__((address_space(1))) void*)(srcb + foff + lane * 4),
            (__attribute__((address_space(3))) void*)(&Hs[foff]),
            16, 0, 0);
      }
    }
    // ---- scores for this tile (M/adj already in regs via prefetch) ----
    const float s0v = s_lds[rb], s1v = s_lds[rb + 16];
    float e0 = (s0v + ncr) * mc0;
    float e1 = (s1v + ncr) * mc1;
    e0 = (e0 > 0.f) ? e0 : 0.2f * e0;
    e1 = (e1 > 0.f) ? e1 : 0.2f * e1;
    e0 = fminf(e0, 70.f);
    e1 = fminf(e1, 70.f);
    const float p0 = (ac0 > 0) ? __expf(e0) : 0.f;
    const float p1 = (ac1 > 0) ? __expf(e1) : 0.f;
    P[rb][c] = p0;
    P[rb + 16][c] = p1;
    float rs0 = p0, rs1 = p1;
    #pragma unroll
    for (int off = 16; off > 0; off >>= 1) {
      rs0 += __shfl_xor(rs0, off);
      rs1 += __shfl_xor(rs1, off);
    }
    if (c == 0) { l_lds[rb] += rs0; l_lds[rb + 16] += rs1; }
    // ---- prefetch next tile's M/adj/n into regs ----
    const int jn = (tj + 1 < NT) ? (j0 + BC) : 0;
    const float mn0 = Mm[row0 + jn], mn1 = Mm[row1 + jn];
    const int   an0 = adj[row0 + jn], an1 = adj[row1 + jn];
    const float nnr = nv[jn + c];
    __syncthreads();   // Hs + P ready
    // ---- PV: acc[32][FOUT] += P[32][32] @ Hs[32][FOUT] ----
    #pragma unroll 8
    for (int k = 0; k < BC; ++k) {
      const float pv0 = P[2 * rb][k];        // broadcast reads, conflict-free
      const float pv1 = P[2 * rb + 1][k];
      #pragma unroll
      for (int chn = 0; chn < NCH; ++chn) {
        float hv[VEC];
        if constexpr (VEC == 4) {
          const float4 tmp = *reinterpret_cast<const float4*>(&Hs[k * FOUT + chn * 128 + 4 * c]);
          hv[0] = tmp.x; hv[1] = tmp.y; hv[2] = tmp.z; hv[3] = tmp.w;
        } else {
          const float2 tmp = *reinterpret_cast<const float2*>(&Hs[k * FOUT + 2 * c]);
          hv[0] = tmp.x; hv[1] = tmp.y;
        }
        #pragma unroll
        for (int v = 0; v < VEC; ++v) {
          acc[0][chn][v] += pv0 * hv[v];
          acc[1][chn][v] += pv1 * hv[v];
        }
      }
    }
    __syncthreads();   // before overwriting P/Hs next iter
    mc0 = mn0; mc1 = mn1; ac0 = an0; ac1 = an1; ncr = nnr;
  }
  // ---- epilogue: divide by softmax denom, elu, store ----
  const float il0 = 1.0f / l_lds[2 * rb];
  const float il1 = 1.0f / l_lds[2 * rb + 1];
  #pragma unroll
  for (int chn = 0; chn < NCH; ++chn) {
    if constexpr (VEC == 4) {
      float4 o0, o1;
      o0.x = eluf(acc[0][chn][0] * il0); o0.y = eluf(acc[0][chn][1] * il0);
      o0.z = eluf(acc[0][chn][2] * il0); o0.w = eluf(acc[0][chn][3] * il0);
      o1.x = eluf(acc[1][chn][0] * il1); o1.y = eluf(acc[1][chn][1] * il1);
      o1.z = eluf(acc[1][chn][2] * il1); o1.w = eluf(acc[1][chn][3] * il1);
      *reinterpret_cast<float4*>(&out[(size_t)(i0 + 2 * rb) * FOUT + chn * 128 + 4 * c]) = o0;
      *reinterpret_cast<float4*>(&out[(size_t)(i0 + 2 * rb + 1) * FOUT + chn * 128 + 4 * c]) = o1;
    } else {
      float2 o0, o1;
      o0.x = eluf(acc[0][chn][0] * il0); o0.y = eluf(acc[0][chn][1] * il0);
      o1.x = eluf(acc[1][chn][0] * il1); o1.y = eluf(acc[1][chn][1] * il1);
      *reinterpret_cast<float2*>(&out[(size_t)(i0 + 2 * rb) * FOUT + 2 * c]) = o0;
      *reinterpret_cast<float2*>(&out[(size_t)(i0 + 2 * rb + 1) * FOUT + 2 * c]) = o1;
    }
  }
}

// ---------------------------------------------------------------------------
extern "C" void kernel_launch(void* const* d_in, const int* in_sizes, int n_in,
                              void* d_out, int out_size, void* d_ws, size_t ws_size,
                              hipStream_t stream) {
  const float* x   = (const float*)d_in[0];
  const int*   adj = (const int*)  d_in[1];
  const float* Mm  = (const float*)d_in[2];
  const float* W0  = (const float*)d_in[3];
  const float* as0 = (const float*)d_in[4];
  const float* an0 = (const float*)d_in[5];
  const float* W1  = (const float*)d_in[6];
  const float* as1 = (const float*)d_in[7];
  const float* an1 = (const float*)d_in[8];
  float* out = (float*)d_out;

  float* h0 = (float*)d_ws;                       // 8192*256
  float* x1 = h0 + (size_t)NNODES * 256;          // 8192*256
  float* s0 = x1 + (size_t)NNODES * 256;
  float* n0 = s0 + NNODES;
  float* s1 = n0 + NNODES;
  float* n1 = s1 + NNODES;
  float* h1 = h0;                                  // reuse: attn1 done reading h0

  // ---- layer 1 ----
  gemm_kernel<512, 256><<<dim3(128, 4), dim3(256), 0, stream>>>(x, W0, h0);
  sn_kernel<256><<<dim3(2048), dim3(256), 0, stream>>>(h0, as0, an0, s0, n0);
  attn_kernel<256><<<dim3(256), dim3(512), 0, stream>>>(Mm, adj, s0, n0, h0, x1);
  // ---- layer 2 ----
  gemm_kernel<256, 64><<<dim3(128, 1), dim3(256), 0, stream>>>(x1, W1, h1);
  sn_kernel<64><<<dim3(2048), dim3(256), 0, stream>>>(h1, as1, an1, s1, n1);
  attn_kernel<64><<<dim3(256), dim3(512), 0, stream>>>(Mm, adj, s1, n1, h1, out);
}

// Round 2
// 619.143 us; speedup vs baseline: 1.8603x; 1.8603x over previous
//
#include <hip/hip_runtime.h>
#include <hip/hip_bf16.h>

constexpr int NN = 8192;

typedef __bf16 bf16x8 __attribute__((ext_vector_type(8)));
typedef float f32x4 __attribute__((ext_vector_type(4)));
typedef float f32x16 __attribute__((ext_vector_type(16)));
typedef unsigned short ushort8_t __attribute__((ext_vector_type(8)));

__device__ __forceinline__ float eluf(float z) { return z > 0.f ? z : __expf(z) - 1.f; }

__device__ __forceinline__ unsigned short bf16_hi(float v) {
  unsigned u = __float_as_uint(v);
  unsigned r = u + 0x7fffu + ((u >> 16) & 1u);
  return (unsigned short)(r >> 16);
}
__device__ __forceinline__ float bf16_tof(unsigned short u) {
  return __uint_as_float(((unsigned)u) << 16);
}

__device__ __forceinline__ void gll16(const void* src, void* ldsdst) {
  __builtin_amdgcn_global_load_lds((__attribute__((address_space(1))) void*)src,
                                   (__attribute__((address_space(3))) void*)ldsdst, 16, 0, 0);
}

// ---------------------------------------------------------------------------
// GEMM: C[M][NOUT] = A[M][K] @ W[K][NOUT]   (fp32, BM=64,BN=64,BK=16, 4x4 micro)
// ---------------------------------------------------------------------------
template<int K, int NOUT>
__global__ __launch_bounds__(256) void gemm_kernel(
    const float* __restrict__ A, const float* __restrict__ W, float* __restrict__ C) {
  constexpr int BM = 64, BN = 64, BK = 16;
  __shared__ __align__(16) float As[BK][BM + 4];
  __shared__ __align__(16) float Ws[BK][BN];
  const int t = threadIdx.x;
  const int i0 = blockIdx.x * BM;
  const int c0 = blockIdx.y * BN;
  const int tr = t >> 4;
  const int tc = t & 15;
  const int lr = t >> 2;
  const int lk = (t & 3) * 4;
  const int wk = t >> 4;
  const int wc = (t & 15) * 4;
  float acc[4][4] = {};
  for (int k0 = 0; k0 < K; k0 += BK) {
    const float4 a4 = *reinterpret_cast<const float4*>(&A[(size_t)(i0 + lr) * K + k0 + lk]);
    As[lk + 0][lr] = a4.x; As[lk + 1][lr] = a4.y;
    As[lk + 2][lr] = a4.z; As[lk + 3][lr] = a4.w;
    *reinterpret_cast<float4*>(&Ws[wk][wc]) =
        *reinterpret_cast<const float4*>(&W[(size_t)(k0 + wk) * NOUT + c0 + wc]);
    __syncthreads();
    #pragma unroll
    for (int kk = 0; kk < BK; ++kk) {
      const float4 av = *reinterpret_cast<const float4*>(&As[kk][4 * tr]);
      const float4 wv = *reinterpret_cast<const float4*>(&Ws[kk][4 * tc]);
      const float a[4] = {av.x, av.y, av.z, av.w};
      const float w[4] = {wv.x, wv.y, wv.z, wv.w};
      #pragma unroll
      for (int i = 0; i < 4; ++i)
        #pragma unroll
        for (int j = 0; j < 4; ++j) acc[i][j] += a[i] * w[j];
    }
    __syncthreads();
  }
  #pragma unroll
  for (int i = 0; i < 4; ++i) {
    const float4 o = make_float4(acc[i][0], acc[i][1], acc[i][2], acc[i][3]);
    *reinterpret_cast<float4*>(&C[(size_t)(i0 + 4 * tr + i) * NOUT + c0 + 4 * tc]) = o;
  }
}

// ---------------------------------------------------------------------------
// s[i] = h[i].a_self ; n[i] = h[i].a_neigh   (one wave per row)
// ---------------------------------------------------------------------------
template<int FOUT>
__global__ __launch_bounds__(256) void sn_kernel(
    const float* __restrict__ H, const float* __restrict__ a_self,
    const float* __restrict__ a_neigh, float* __restrict__ s, float* __restrict__ n) {
  const int wave = threadIdx.x >> 6;
  const int lane = threadIdx.x & 63;
  const int row = blockIdx.x * 4 + wave;
  float ds = 0.f, dn = 0.f;
  #pragma unroll
  for (int c = lane; c < FOUT; c += 64) {
    const float h = H[(size_t)row * FOUT + c];
    ds += h * a_self[c];
    dn += h * a_neigh[c];
  }
  #pragma unroll
  for (int off = 32; off > 0; off >>= 1) {
    ds += __shfl_down(ds, off);
    dn += __shfl_down(dn, off);
  }
  if (lane == 0) { s[row] = ds; n[row] = dn; }
}

// ---------------------------------------------------------------------------
// Split H (fp32 [N][F]) into hi/lo bf16 in MFMA-staging layout:
//   T[tile=j/32][kc=0..3][col=0..F-1][e=0..7]  (element j = tile*32+kc*8+e)
// ---------------------------------------------------------------------------
template<int F>
__global__ __launch_bounds__(256) void split_kernel(
    const float* __restrict__ H, unsigned short* __restrict__ Th,
    unsigned short* __restrict__ Tl) {
  const int t = threadIdx.x;
  const int tile = blockIdx.x;
  const int c = t & (F - 1);
  const int kcb = t / F;
  for (int kc = kcb; kc < 4; kc += 256 / F) {
    ushort8_t hi, lo;
    #pragma unroll
    for (int e = 0; e < 8; ++e) {
      float v = H[(size_t)(tile * 32 + kc * 8 + e) * F + c];
      unsigned short h = bf16_hi(v);
      hi[e] = h;
      lo[e] = bf16_hi(v - bf16_tof(h));
    }
    size_t o = ((size_t)(tile * 4 + kc) * F + c) * 8;
    *reinterpret_cast<ushort8_t*>(&Th[o]) = hi;
    *reinterpret_cast<ushort8_t*>(&Tl[o]) = lo;
  }
}

// ---------------------------------------------------------------------------
// Layer-1 fused attention: F=256, BR=32 rows/block, 1024 thr (16 waves).
// mfma_f32_32x32x16_bf16, col-frag cf = w&7 (32 cols), k-split ks = w>>3.
// bf16x3: acc += Ph*Hh + Ph*Hl + Pl*Hh.
// ---------------------------------------------------------------------------
__global__ __launch_bounds__(1024) void attn1_kernel(
    const float* __restrict__ Mm, const int* __restrict__ adj,
    const float* __restrict__ sv, const float* __restrict__ nv,
    const unsigned short* __restrict__ Th, const unsigned short* __restrict__ Tl,
    float* __restrict__ out) {
  constexpr int F = 256, BR = 32, BC = 32, NT = NN / BC;
  __shared__ unsigned short Bs[2][2][4 * F * 8];   // [buf][part] 16KB each
  __shared__ unsigned short Pa[2][4 * BR * 8];     // [part][(kc*32+row)*8+e]
  __shared__ float s_lds[BR];
  __shared__ float l_lds[BR];

  const int t = threadIdx.x;
  const int lane = t & 63;
  const int w = t >> 6;        // 0..15
  const int r = t >> 5;        // 0..31 score row
  const int c = t & 31;        // score col (k within tile)
  const int i0 = blockIdx.x * BR;
  const int cf = w & 7;        // col-frag (32 cols)
  const int ks = w >> 3;       // k-split half

  if (t < BR) s_lds[t] = sv[i0 + t];

  const size_t rowoff = (size_t)(i0 + r) * NN;
  float mc = Mm[rowoff + c];
  int ac = adj[rowoff + c];
  float ncr = nv[c];

  // prologue: stage tile 0
  {
    const size_t chunk = (size_t)w * 64 + lane;
    gll16(Th + chunk * 8, &Bs[0][0][w * 512]);
    gll16(Tl + chunk * 8, &Bs[0][1][w * 512]);
  }
  float rsum = 0.f;
  f32x16 acc;
  #pragma unroll
  for (int i = 0; i < 16; ++i) acc[i] = 0.f;

  __syncthreads();

  for (int tj = 0; tj < NT; ++tj) {
    const int buf = tj & 1;
    const int j = tj * BC;
    if (tj + 1 < NT) {
      const size_t chunk = (size_t)(tj + 1) * 1024 + w * 64 + lane;
      gll16(Th + chunk * 8, &Bs[buf ^ 1][0][w * 512]);
      gll16(Tl + chunk * 8, &Bs[buf ^ 1][1][w * 512]);
    }
    // prefetch next M/adj/n
    const int jn = (tj + 1 < NT) ? j + BC : 0;
    const float mn = Mm[rowoff + jn + c];
    const int an = adj[rowoff + jn + c];
    const float nnv = nv[jn + c];
    // score
    float e0 = (s_lds[r] + ncr) * mc;
    e0 = (e0 > 0.f) ? e0 : 0.2f * e0;
    e0 = fminf(e0, 70.f);
    const float p = (ac > 0) ? __expf(e0) : 0.f;
    rsum += p;
    const unsigned short ph = bf16_hi(p);
    const unsigned short pl = bf16_hi(p - bf16_tof(ph));
    const int poff = ((c >> 3) * 32 + r) * 8 + (c & 7);
    Pa[0][poff] = ph;
    Pa[1][poff] = pl;
    __syncthreads();
    // MFMA (this wave's 16-k slice)
    const int akc = ks * 2 + (lane >> 5);
    const int aoff = (akc * 32 + (lane & 31)) * 8;
    const bf16x8 ah = *reinterpret_cast<const bf16x8*>(&Pa[0][aoff]);
    const bf16x8 al = *reinterpret_cast<const bf16x8*>(&Pa[1][aoff]);
    const int boff = (akc * F + cf * 32 + (lane & 31)) * 8;
    const bf16x8 bh = *reinterpret_cast<const bf16x8*>(&Bs[buf][0][boff]);
    const bf16x8 bl = *reinterpret_cast<const bf16x8*>(&Bs[buf][1][boff]);
    acc = __builtin_amdgcn_mfma_f32_32x32x16_bf16(al, bh, acc, 0, 0, 0);
    acc = __builtin_amdgcn_mfma_f32_32x32x16_bf16(ah, bl, acc, 0, 0, 0);
    acc = __builtin_amdgcn_mfma_f32_32x32x16_bf16(ah, bh, acc, 0, 0, 0);
    __syncthreads();
    mc = mn; ac = an; ncr = nnv;
  }

  // rowsum: reduce across the 32 score-columns (lanes within 32-half)
  #pragma unroll
  for (int off = 16; off > 0; off >>= 1) rsum += __shfl_xor(rsum, off);
  if (c == 0) l_lds[r] = rsum;

  // k-split reduction through LDS (reuse Bs as scratch)
  float* scratch = reinterpret_cast<float*>(&Bs[0][0][0]);
  if (ks == 1) {
    #pragma unroll
    for (int i = 0; i < 16; ++i) scratch[cf * 1024 + i * 64 + lane] = acc[i];
  }
  __syncthreads();
  if (ks == 0) {
    const int col = cf * 32 + (lane & 31);
    #pragma unroll
    for (int i = 0; i < 16; ++i) {
      const int row = (i & 3) + 8 * (i >> 2) + 4 * (lane >> 5);
      float v = acc[i] + scratch[cf * 1024 + i * 64 + lane];
      v = v / l_lds[row];
      out[(size_t)(i0 + row) * F + col] = eluf(v);
    }
  }
}

// ---------------------------------------------------------------------------
// Layer-2 fused attention: F=64, BR=16 rows/block, 256 thr (4 waves).
// mfma_f32_16x16x32_bf16, col-frag cf = w (16 cols), no k-split.
// ---------------------------------------------------------------------------
__global__ __launch_bounds__(256) void attn2_kernel(
    const float* __restrict__ Mm, const int* __restrict__ adj,
    const float* __restrict__ sv, const float* __restrict__ nv,
    const unsigned short* __restrict__ Th, const unsigned short* __restrict__ Tl,
    float* __restrict__ out) {
  constexpr int F = 64, BR = 16, BC = 32, NT = NN / BC;
  __shared__ unsigned short Bs[2][2][4 * F * 8];   // 4KB each
  __shared__ unsigned short Pa[2][4 * BR * 8];     // 1KB each
  __shared__ float s_lds[BR];
  __shared__ float l_lds[BR];

  const int t = threadIdx.x;
  const int lane = t & 63;
  const int w = t >> 6;      // 0..3 == col-frag
  const int r0 = t >> 5;     // 0..7 -> rows r0, r0+8
  const int c = t & 31;
  const int i0 = blockIdx.x * BR;

  if (t < BR) s_lds[t] = sv[i0 + t];

  const size_t rowoff0 = (size_t)(i0 + r0) * NN;
  const size_t rowoff1 = rowoff0 + (size_t)8 * NN;
  float mc0 = Mm[rowoff0 + c], mc1 = Mm[rowoff1 + c];
  int ac0 = adj[rowoff0 + c], ac1 = adj[rowoff1 + c];
  float ncr = nv[c];

  {
    const size_t chunk = (size_t)w * 64 + lane;
    gll16(Th + chunk * 8, &Bs[0][0][w * 512]);
    gll16(Tl + chunk * 8, &Bs[0][1][w * 512]);
  }
  float rs0 = 0.f, rs1 = 0.f;
  f32x4 acc = {0.f, 0.f, 0.f, 0.f};

  __syncthreads();

  for (int tj = 0; tj < NT; ++tj) {
    const int buf = tj & 1;
    const int j = tj * BC;
    if (tj + 1 < NT) {
      const size_t chunk = (size_t)(tj + 1) * 256 + w * 64 + lane;
      gll16(Th + chunk * 8, &Bs[buf ^ 1][0][w * 512]);
      gll16(Tl + chunk * 8, &Bs[buf ^ 1][1][w * 512]);
    }
    const int jn = (tj + 1 < NT) ? j + BC : 0;
    const float mn0 = Mm[rowoff0 + jn + c], mn1 = Mm[rowoff1 + jn + c];
    const int an0 = adj[rowoff0 + jn + c], an1 = adj[rowoff1 + jn + c];
    const float nnv = nv[jn + c];

    float e0 = (s_lds[r0] + ncr) * mc0;
    float e1 = (s_lds[r0 + 8] + ncr) * mc1;
    e0 = (e0 > 0.f) ? e0 : 0.2f * e0;
    e1 = (e1 > 0.f) ? e1 : 0.2f * e1;
    e0 = fminf(e0, 70.f);
    e1 = fminf(e1, 70.f);
    const float p0 = (ac0 > 0) ? __expf(e0) : 0.f;
    const float p1 = (ac1 > 0) ? __expf(e1) : 0.f;
    rs0 += p0; rs1 += p1;
    const unsigned short p0h = bf16_hi(p0);
    const unsigned short p0l = bf16_hi(p0 - bf16_tof(p0h));
    const unsigned short p1h = bf16_hi(p1);
    const unsigned short p1l = bf16_hi(p1 - bf16_tof(p1h));
    const int po0 = ((c >> 3) * 16 + r0) * 8 + (c & 7);
    const int po1 = ((c >> 3) * 16 + r0 + 8) * 8 + (c & 7);
    Pa[0][po0] = p0h; Pa[1][po0] = p0l;
    Pa[0][po1] = p1h; Pa[1][po1] = p1l;
    __syncthreads();

    const bf16x8 ah = *reinterpret_cast<const bf16x8*>(&Pa[0][lane * 8]);
    const bf16x8 al = *reinterpret_cast<const bf16x8*>(&Pa[1][lane * 8]);
    const int boff = ((lane >> 4) * F + w * 16 + (lane & 15)) * 8;
    const bf16x8 bh = *reinterpret_cast<const bf16x8*>(&Bs[buf][0][boff]);
    const bf16x8 bl = *reinterpret_cast<const bf16x8*>(&Bs[buf][1][boff]);
    acc = __builtin_amdgcn_mfma_f32_16x16x32_bf16(al, bh, acc, 0, 0, 0);
    acc = __builtin_amdgcn_mfma_f32_16x16x32_bf16(ah, bl, acc, 0, 0, 0);
    acc = __builtin_amdgcn_mfma_f32_16x16x32_bf16(ah, bh, acc, 0, 0, 0);
    __syncthreads();
    mc0 = mn0; mc1 = mn1; ac0 = an0; ac1 = an1; ncr = nnv;
  }

  #pragma unroll
  for (int off = 16; off > 0; off >>= 1) {
    rs0 += __shfl_xor(rs0, off);
    rs1 += __shfl_xor(rs1, off);
  }
  if (c == 0) { l_lds[r0] = rs0; l_lds[r0 + 8] = rs1; }
  __syncthreads();

  const int col = w * 16 + (lane & 15);
  #pragma unroll
  for (int reg = 0; reg < 4; ++reg) {
    const int row = (lane >> 4) * 4 + reg;
    float v = acc[reg] / l_lds[row];
    out[(size_t)(i0 + row) * F + col] = eluf(v);
  }
}

// ---------------------------------------------------------------------------
extern "C" void kernel_launch(void* const* d_in, const int* in_sizes, int n_in,
                              void* d_out, int out_size, void* d_ws, size_t ws_size,
                              hipStream_t stream) {
  const float* x   = (const float*)d_in[0];
  const int*   adj = (const int*)  d_in[1];
  const float* Mm  = (const float*)d_in[2];
  const float* W0  = (const float*)d_in[3];
  const float* as0 = (const float*)d_in[4];
  const float* an0 = (const float*)d_in[5];
  const float* W1  = (const float*)d_in[6];
  const float* as1 = (const float*)d_in[7];
  const float* an1 = (const float*)d_in[8];
  float* out = (float*)d_out;

  char* ws = (char*)d_ws;
  const size_t MB = 1048576;
  float* h0  = (float*)(ws);                 // 8 MB
  float* x1  = (float*)(ws + 8 * MB);        // 8 MB
  float* h1  = (float*)(ws + 16 * MB);       // 2 MB
  unsigned short* Th0 = (unsigned short*)(ws + 18 * MB);  // 4 MB
  unsigned short* Tl0 = (unsigned short*)(ws + 22 * MB);  // 4 MB
  unsigned short* Th1 = (unsigned short*)(ws + 26 * MB);  // 1 MB
  unsigned short* Tl1 = (unsigned short*)(ws + 27 * MB);  // 1 MB
  float* s0 = (float*)(ws + 28 * MB);
  float* n0 = s0 + NN;
  float* s1 = n0 + NN;
  float* n1 = s1 + NN;

  // ---- layer 1 ----
  gemm_kernel<512, 256><<<dim3(128, 4), dim3(256), 0, stream>>>(x, W0, h0);
  sn_kernel<256><<<dim3(2048), dim3(256), 0, stream>>>(h0, as0, an0, s0, n0);
  split_kernel<256><<<dim3(256), dim3(256), 0, stream>>>(h0, Th0, Tl0);
  attn1_kernel<<<dim3(256), dim3(1024), 0, stream>>>(Mm, adj, s0, n0, Th0, Tl0, x1);
  // ---- layer 2 ----
  gemm_kernel<256, 64><<<dim3(128, 1), dim3(256), 0, stream>>>(x1, W1, h1);
  sn_kernel<64><<<dim3(2048), dim3(256), 0, stream>>>(h1, as1, an1, s1, n1);
  split_kernel<64><<<dim3(256), dim3(256), 0, stream>>>(h1, Th1, Tl1);
  attn2_kernel<<<dim3(512), dim3(256), 0, stream>>>(Mm, adj, s1, n1, Th1, Tl1, out);
}

// Round 4
// 466.325 us; speedup vs baseline: 2.4699x; 1.3277x over previous
//
#include <hip/hip_runtime.h>
#include <hip/hip_bf16.h>

constexpr int NN = 8192;
using uint = unsigned int;

typedef __bf16 bf16x8 __attribute__((ext_vector_type(8)));
typedef float f32x4 __attribute__((ext_vector_type(4)));
typedef float f32x16 __attribute__((ext_vector_type(16)));
typedef unsigned short ushort8_t __attribute__((ext_vector_type(8)));

__device__ __forceinline__ float eluf(float z) { return z > 0.f ? z : __expf(z) - 1.f; }

__device__ __forceinline__ unsigned short bf16_hi(float v) {
  unsigned u = __float_as_uint(v);
  unsigned r = u + 0x7fffu + ((u >> 16) & 1u);
  return (unsigned short)(r >> 16);
}
__device__ __forceinline__ float bf16_tof(unsigned short u) {
  return __uint_as_float(((unsigned)u) << 16);
}

// ---------------------------------------------------------------------------
// GEMM: C[M][NOUT] = A[M][K] @ W[K][NOUT]   (fp32, BM=64,BN=64,BK=16, 4x4 micro)
// ---------------------------------------------------------------------------
template<int K, int NOUT>
__global__ __launch_bounds__(256) void gemm_kernel(
    const float* __restrict__ A, const float* __restrict__ W, float* __restrict__ C) {
  constexpr int BM = 64, BN = 64, BK = 16;
  __shared__ __align__(16) float As[BK][BM + 4];
  __shared__ __align__(16) float Ws[BK][BN];
  const int t = threadIdx.x;
  const int i0 = blockIdx.x * BM;
  const int c0 = blockIdx.y * BN;
  const int tr = t >> 4;
  const int tc = t & 15;
  const int lr = t >> 2;
  const int lk = (t & 3) * 4;
  const int wk = t >> 4;
  const int wc = (t & 15) * 4;
  float acc[4][4] = {};
  for (int k0 = 0; k0 < K; k0 += BK) {
    const float4 a4 = *reinterpret_cast<const float4*>(&A[(size_t)(i0 + lr) * K + k0 + lk]);
    As[lk + 0][lr] = a4.x; As[lk + 1][lr] = a4.y;
    As[lk + 2][lr] = a4.z; As[lk + 3][lr] = a4.w;
    *reinterpret_cast<float4*>(&Ws[wk][wc]) =
        *reinterpret_cast<const float4*>(&W[(size_t)(k0 + wk) * NOUT + c0 + wc]);
    __syncthreads();
    #pragma unroll
    for (int kk = 0; kk < BK; ++kk) {
      const float4 av = *reinterpret_cast<const float4*>(&As[kk][4 * tr]);
      const float4 wv = *reinterpret_cast<const float4*>(&Ws[kk][4 * tc]);
      const float a[4] = {av.x, av.y, av.z, av.w};
      const float w[4] = {wv.x, wv.y, wv.z, wv.w};
      #pragma unroll
      for (int i = 0; i < 4; ++i)
        #pragma unroll
        for (int j = 0; j < 4; ++j) acc[i][j] += a[i] * w[j];
    }
    __syncthreads();
  }
  #pragma unroll
  for (int i = 0; i < 4; ++i) {
    const float4 o = make_float4(acc[i][0], acc[i][1], acc[i][2], acc[i][3]);
    *reinterpret_cast<float4*>(&C[(size_t)(i0 + 4 * tr + i) * NOUT + c0 + 4 * tc]) = o;
  }
}

// ---------------------------------------------------------------------------
// s[i] = h[i].a_self ; n[i] = h[i].a_neigh   (one wave per row)
// ---------------------------------------------------------------------------
template<int FOUT>
__global__ __launch_bounds__(256) void sn_kernel(
    const float* __restrict__ H, const float* __restrict__ a_self,
    const float* __restrict__ a_neigh, float* __restrict__ s, float* __restrict__ n) {
  const int wave = threadIdx.x >> 6;
  const int lane = threadIdx.x & 63;
  const int row = blockIdx.x * 4 + wave;
  float ds = 0.f, dn = 0.f;
  #pragma unroll
  for (int c = lane; c < FOUT; c += 64) {
    const float h = H[(size_t)row * FOUT + c];
    ds += h * a_self[c];
    dn += h * a_neigh[c];
  }
  #pragma unroll
  for (int off = 32; off > 0; off >>= 1) {
    ds += __shfl_down(ds, off);
    dn += __shfl_down(dn, off);
  }
  if (lane == 0) { s[row] = ds; n[row] = dn; }
}

// ---------------------------------------------------------------------------
// Split H (fp32 [N][F]) into hi/lo bf16 in MFMA-staging layout:
//   T[tile=j/32][kc8=0..3][col=0..F-1][e=0..7]  (element j = tile*32+kc8*8+e)
// ---------------------------------------------------------------------------
template<int F>
__global__ __launch_bounds__(256) void split_kernel(
    const float* __restrict__ H, unsigned short* __restrict__ Th,
    unsigned short* __restrict__ Tl) {
  const int t = threadIdx.x;
  const int tile = blockIdx.x;
  const int c = t & (F - 1);
  const int kcb = t / F;
  for (int kc = kcb; kc < 4; kc += 256 / F) {
    ushort8_t hi, lo;
    #pragma unroll
    for (int e = 0; e < 8; ++e) {
      float v = H[(size_t)(tile * 32 + kc * 8 + e) * F + c];
      unsigned short h = bf16_hi(v);
      hi[e] = h;
      lo[e] = bf16_hi(v - bf16_tof(h));
    }
    size_t o = ((size_t)(tile * 4 + kc) * F + c) * 8;
    *reinterpret_cast<ushort8_t*>(&Th[o]) = hi;
    *reinterpret_cast<ushort8_t*>(&Tl[o]) = lo;
  }
}

// ---------------------------------------------------------------------------
// adj (int32 0/1) -> bitmask, word W covers cols [W*32, W*32+32) of a row.
// ---------------------------------------------------------------------------
__global__ __launch_bounds__(256) void mask_kernel(
    const int* __restrict__ adj, uint* __restrict__ Bm) {
  const size_t tg = (size_t)blockIdx.x * 256 + threadIdx.x;
  const int4 a = *reinterpret_cast<const int4*>(&adj[tg * 4]);
  uint nib = (a.x > 0 ? 1u : 0u) | (a.y > 0 ? 2u : 0u) |
             (a.z > 0 ? 4u : 0u) | (a.w > 0 ? 8u : 0u);
  const int lane = threadIdx.x & 63;
  uint v = nib << ((lane & 7) * 4);
  v |= __shfl_xor(v, 1);
  v |= __shfl_xor(v, 2);
  v |= __shfl_xor(v, 4);
  if ((lane & 7) == 0) Bm[tg >> 3] = v;
}

// ---------------------------------------------------------------------------
// Layer-1 fused attention. F=256, BR=32, 512 thr (8 waves), one barrier/tile.
// Wave w = col-frag (32 cols), full K per wave via 2 sub-MFMAs (32x32x16).
// B-frags global->reg (L2-resident), prefetch 1 tile; M/mask prefetch 2 tiles.
// ---------------------------------------------------------------------------
__global__ __launch_bounds__(512) void attn1_kernel(
    const float* __restrict__ Mm, const uint* __restrict__ Bm,
    const float* __restrict__ sv, const float* __restrict__ nv,
    const unsigned short* __restrict__ Th, const unsigned short* __restrict__ Tl,
    float* __restrict__ out) {
  constexpr int F = 256, BR = 32, NT = NN / 32;
  __shared__ __align__(16) uint Pa[2][2][512];  // [buf][hi/lo][(kc8*32+row)*4+quad]
  __shared__ float nvs[NN];
  __shared__ float l_lds[BR];

  const int t = threadIdx.x;
  const int lane = t & 63;
  const int cf = t >> 6;             // wave = col-frag
  const int r = t >> 4;              // score row 0..31
  const int p2 = t & 15;             // col pair: cols 2p2, 2p2+1
  const int i0 = blockIdx.x * BR;

  for (int i = t; i < NN / 4; i += 512)
    reinterpret_cast<float4*>(nvs)[i] = reinterpret_cast<const float4*>(nv)[i];

  const float svr = sv[i0 + r];
  const size_t mrow = (size_t)(i0 + r) * NN;
  const uint* mkrow = Bm + (size_t)(i0 + r) * (NN / 32);
  const int col = cf * 32 + (lane & 31);
  const size_t bo0 = ((size_t)(lane >> 5) * F + col) * 8;  // kc8 in {0,1}; +4096 for {2,3}
  const int pidx = ((p2 >> 2) * 32 + r) * 4 + (p2 & 3);
  const int aidx = ((lane >> 5) * 32 + (lane & 31)) * 4;

  float2 M_e = *reinterpret_cast<const float2*>(&Mm[mrow + 2 * p2]);
  float2 M_o = *reinterpret_cast<const float2*>(&Mm[mrow + 32 + 2 * p2]);
  uint mk_e = mkrow[0];
  uint mk_o = mkrow[1];
  bf16x8 bh0_e = *reinterpret_cast<const bf16x8*>(Th + bo0);
  bf16x8 bl0_e = *reinterpret_cast<const bf16x8*>(Tl + bo0);
  bf16x8 bh1_e = *reinterpret_cast<const bf16x8*>(Th + bo0 + 4096);
  bf16x8 bl1_e = *reinterpret_cast<const bf16x8*>(Tl + bo0 + 4096);
  bf16x8 bh0_o, bl0_o, bh1_o, bl1_o;

  float rsum = 0.f;
  f32x16 acc;
  #pragma unroll
  for (int i = 0; i < 16; ++i) acc[i] = 0.f;

  __syncthreads();

#define STEP1(TJ, MC, MKC, BH0C, BL0C, BH1C, BL1C, BH0N, BL0N, BH1N, BL1N)        \
  {                                                                               \
    const int t_j = (TJ);                                                         \
    const int jb = (t_j + 1 < NT) ? t_j + 1 : 0;                                  \
    const size_t tb = (size_t)jb * 8192;                                          \
    BH0N = *reinterpret_cast<const bf16x8*>(Th + tb + bo0);                       \
    BL0N = *reinterpret_cast<const bf16x8*>(Tl + tb + bo0);                       \
    BH1N = *reinterpret_cast<const bf16x8*>(Th + tb + bo0 + 4096);                \
    BL1N = *reinterpret_cast<const bf16x8*>(Tl + tb + bo0 + 4096);                \
    const int jm = (t_j + 2 < NT) ? t_j + 2 : 0;                                  \
    const float2 Mnew = *reinterpret_cast<const float2*>(&Mm[mrow + (size_t)jm * 32 + 2 * p2]); \
    const uint mknew = mkrow[jm];                                                 \
    const float nv0 = nvs[t_j * 32 + 2 * p2];                                     \
    const float nv1 = nvs[t_j * 32 + 2 * p2 + 1];                                 \
    float e0 = (svr + nv0) * MC.x; e0 = fmaxf(e0, 0.2f * e0); e0 = fminf(e0, 70.f); \
    float e1 = (svr + nv1) * MC.y; e1 = fmaxf(e1, 0.2f * e1); e1 = fminf(e1, 70.f); \
    const float p0 = ((MKC >> (2 * p2)) & 1u) ? __expf(e0) : 0.f;                 \
    const float p1 = ((MKC >> (2 * p2 + 1)) & 1u) ? __expf(e1) : 0.f;             \
    rsum += p0 + p1;                                                              \
    const unsigned short h0 = bf16_hi(p0), h1 = bf16_hi(p1);                      \
    const uint hw = (uint)h0 | ((uint)h1 << 16);                                  \
    const uint lw = (uint)bf16_hi(p0 - bf16_tof(h0)) |                            \
                    ((uint)bf16_hi(p1 - bf16_tof(h1)) << 16);                     \
    Pa[t_j & 1][0][pidx] = hw;                                                    \
    Pa[t_j & 1][1][pidx] = lw;                                                    \
    MC = Mnew; MKC = mknew;                                                       \
    __syncthreads();                                                              \
    const uint* pb0 = &Pa[t_j & 1][0][0];                                         \
    const uint* pb1 = &Pa[t_j & 1][1][0];                                         \
    const bf16x8 ah0 = *reinterpret_cast<const bf16x8*>(&pb0[aidx]);              \
    const bf16x8 al0 = *reinterpret_cast<const bf16x8*>(&pb1[aidx]);              \
    const bf16x8 ah1 = *reinterpret_cast<const bf16x8*>(&pb0[aidx + 256]);        \
    const bf16x8 al1 = *reinterpret_cast<const bf16x8*>(&pb1[aidx + 256]);        \
    acc = __builtin_amdgcn_mfma_f32_32x32x16_bf16(al0, BH0C, acc, 0, 0, 0);       \
    acc = __builtin_amdgcn_mfma_f32_32x32x16_bf16(ah0, BL0C, acc, 0, 0, 0);       \
    acc = __builtin_amdgcn_mfma_f32_32x32x16_bf16(ah0, BH0C, acc, 0, 0, 0);       \
    acc = __builtin_amdgcn_mfma_f32_32x32x16_bf16(al1, BH1C, acc, 0, 0, 0);       \
    acc = __builtin_amdgcn_mfma_f32_32x32x16_bf16(ah1, BL1C, acc, 0, 0, 0);       \
    acc = __builtin_amdgcn_mfma_f32_32x32x16_bf16(ah1, BH1C, acc, 0, 0, 0);       \
  }

  for (int tj = 0; tj < NT; tj += 2) {
    STEP1(tj,     M_e, mk_e, bh0_e, bl0_e, bh1_e, bl1_e, bh0_o, bl0_o, bh1_o, bl1_o)
    STEP1(tj + 1, M_o, mk_o, bh0_o, bl0_o, bh1_o, bl1_o, bh0_e, bl0_e, bh1_e, bl1_e)
  }
#undef STEP1

  #pragma unroll
  for (int off = 1; off < 16; off <<= 1) rsum += __shfl_xor(rsum, off);
  if (p2 == 0) l_lds[r] = rsum;
  __syncthreads();

  #pragma unroll
  for (int reg = 0; reg < 16; ++reg) {
    const int row = (reg & 3) + 8 * (reg >> 2) + 4 * (lane >> 5);
    const float v = acc[reg] / l_lds[row];
    out[(size_t)(i0 + row) * F + col] = eluf(v);
  }
}

// ---------------------------------------------------------------------------
// Layer-2 fused attention. F=64, BR=32, 512 thr (8 waves): rb=w&1 (16-row
// frag), cf=w>>1 (16-col frag), mfma_f32_16x16x32_bf16, full K per wave.
// ---------------------------------------------------------------------------
__global__ __launch_bounds__(512) void attn2_kernel(
    const float* __restrict__ Mm, const uint* __restrict__ Bm,
    const float* __restrict__ sv, const float* __restrict__ nv,
    const unsigned short* __restrict__ Th, const unsigned short* __restrict__ Tl,
    float* __restrict__ out) {
  constexpr int F = 64, BR = 32, NT = NN / 32;
  __shared__ __align__(16) uint Pa[2][2][512];
  __shared__ float nvs[NN];
  __shared__ float l_lds[BR];

  const int t = threadIdx.x;
  const int lane = t & 63;
  const int w = t >> 6;
  const int rb = w & 1;
  const int cf = w >> 1;
  const int r = t >> 4;
  const int p2 = t & 15;
  const int i0 = blockIdx.x * BR;

  for (int i = t; i < NN / 4; i += 512)
    reinterpret_cast<float4*>(nvs)[i] = reinterpret_cast<const float4*>(nv)[i];

  const float svr = sv[i0 + r];
  const size_t mrow = (size_t)(i0 + r) * NN;
  const uint* mkrow = Bm + (size_t)(i0 + r) * (NN / 32);
  const int col = cf * 16 + (lane & 15);
  const size_t bo2 = ((size_t)(lane >> 4) * F + col) * 8;
  const int pidx = ((p2 >> 2) * 32 + r) * 4 + (p2 & 3);
  const int aidx = ((lane >> 4) * 32 + rb * 16 + (lane & 15)) * 4;

  float2 M_e = *reinterpret_cast<const float2*>(&Mm[mrow + 2 * p2]);
  float2 M_o = *reinterpret_cast<const float2*>(&Mm[mrow + 32 + 2 * p2]);
  uint mk_e = mkrow[0];
  uint mk_o = mkrow[1];
  bf16x8 bh_e = *reinterpret_cast<const bf16x8*>(Th + bo2);
  bf16x8 bl_e = *reinterpret_cast<const bf16x8*>(Tl + bo2);
  bf16x8 bh_o, bl_o;

  float rsum = 0.f;
  f32x4 acc = {0.f, 0.f, 0.f, 0.f};

  __syncthreads();

#define STEP2(TJ, MC, MKC, BHC, BLC, BHN, BLN)                                    \
  {                                                                               \
    const int t_j = (TJ);                                                         \
    const int jb = (t_j + 1 < NT) ? t_j + 1 : 0;                                  \
    const size_t tb = (size_t)jb * 2048;                                          \
    BHN = *reinterpret_cast<const bf16x8*>(Th + tb + bo2);                        \
    BLN = *reinterpret_cast<const bf16x8*>(Tl + tb + bo2);                        \
    const int jm = (t_j + 2 < NT) ? t_j + 2 : 0;                                  \
    const float2 Mnew = *reinterpret_cast<const float2*>(&Mm[mrow + (size_t)jm * 32 + 2 * p2]); \
    const uint mknew = mkrow[jm];                                                 \
    const float nv0 = nvs[t_j * 32 + 2 * p2];                                     \
    const float nv1 = nvs[t_j * 32 + 2 * p2 + 1];                                 \
    float e0 = (svr + nv0) * MC.x; e0 = fmaxf(e0, 0.2f * e0); e0 = fminf(e0, 70.f); \
    float e1 = (svr + nv1) * MC.y; e1 = fmaxf(e1, 0.2f * e1); e1 = fminf(e1, 70.f); \
    const float p0 = ((MKC >> (2 * p2)) & 1u) ? __expf(e0) : 0.f;                 \
    const float p1 = ((MKC >> (2 * p2 + 1)) & 1u) ? __expf(e1) : 0.f;             \
    rsum += p0 + p1;                                                              \
    const unsigned short h0 = bf16_hi(p0), h1 = bf16_hi(p1);                      \
    const uint hw = (uint)h0 | ((uint)h1 << 16);                                  \
    const uint lw = (uint)bf16_hi(p0 - bf16_tof(h0)) |                            \
                    ((uint)bf16_hi(p1 - bf16_tof(h1)) << 16);                     \
    Pa[t_j & 1][0][pidx] = hw;                                                    \
    Pa[t_j & 1][1][pidx] = lw;                                                    \
    MC = Mnew; MKC = mknew;                                                       \
    __syncthreads();                                                              \
    const bf16x8 ah = *reinterpret_cast<const bf16x8*>(&Pa[t_j & 1][0][aidx]);    \
    const bf16x8 al = *reinterpret_cast<const bf16x8*>(&Pa[t_j & 1][1][aidx]);    \
    acc = __builtin_amdgcn_mfma_f32_16x16x32_bf16(al, BHC, acc, 0, 0, 0);         \
    acc = __builtin_amdgcn_mfma_f32_16x16x32_bf16(ah, BLC, acc, 0, 0, 0);         \
    acc = __builtin_amdgcn_mfma_f32_16x16x32_bf16(ah, BHC, acc, 0, 0, 0);         \
  }

  for (int tj = 0; tj < NT; tj += 2) {
    STEP2(tj,     M_e, mk_e, bh_e, bl_e, bh_o, bl_o)
    STEP2(tj + 1, M_o, mk_o, bh_o, bl_o, bh_e, bl_e)
  }
#undef STEP2

  #pragma unroll
  for (int off = 1; off < 16; off <<= 1) rsum += __shfl_xor(rsum, off);
  if (p2 == 0) l_lds[r] = rsum;
  __syncthreads();

  #pragma unroll
  for (int reg = 0; reg < 4; ++reg) {
    const int row = rb * 16 + (lane >> 4) * 4 + reg;
    const float v = acc[reg] / l_lds[row];
    out[(size_t)(i0 + row) * F + col] = eluf(v);
  }
}

// ---------------------------------------------------------------------------
extern "C" void kernel_launch(void* const* d_in, const int* in_sizes, int n_in,
                              void* d_out, int out_size, void* d_ws, size_t ws_size,
                              hipStream_t stream) {
  const float* x   = (const float*)d_in[0];
  const int*   adj = (const int*)  d_in[1];
  const float* Mm  = (const float*)d_in[2];
  const float* W0  = (const float*)d_in[3];
  const float* as0 = (const float*)d_in[4];
  const float* an0 = (const float*)d_in[5];
  const float* W1  = (const float*)d_in[6];
  const float* as1 = (const float*)d_in[7];
  const float* an1 = (const float*)d_in[8];
  float* out = (float*)d_out;

  char* ws = (char*)d_ws;
  const size_t MB = 1048576;
  float* h0  = (float*)(ws);                              // 8 MB (dead after split1)
  uint*  Bm  = (uint*) (ws);                              // 8 MB (written after split1)
  float* x1  = (float*)(ws + 8 * MB);                     // 8 MB
  float* h1  = (float*)(ws + 16 * MB);                    // 2 MB
  unsigned short* Th0 = (unsigned short*)(ws + 18 * MB);  // 4 MB
  unsigned short* Tl0 = (unsigned short*)(ws + 22 * MB);  // 4 MB
  unsigned short* Th1 = (unsigned short*)(ws + 26 * MB);  // 1 MB
  unsigned short* Tl1 = (unsigned short*)(ws + 27 * MB);  // 1 MB
  float* s0 = (float*)(ws + 28 * MB);
  float* n0 = s0 + NN;
  float* s1 = n0 + NN;
  float* n1 = s1 + NN;

  // ---- layer 1 ----
  gemm_kernel<512, 256><<<dim3(128, 4), dim3(256), 0, stream>>>(x, W0, h0);
  sn_kernel<256><<<dim3(2048), dim3(256), 0, stream>>>(h0, as0, an0, s0, n0);
  split_kernel<256><<<dim3(256), dim3(256), 0, stream>>>(h0, Th0, Tl0);
  mask_kernel<<<dim3(65536), dim3(256), 0, stream>>>(adj, Bm);   // h0 now dead
  attn1_kernel<<<dim3(256), dim3(512), 0, stream>>>(Mm, Bm, s0, n0, Th0, Tl0, x1);
  // ---- layer 2 ----
  gemm_kernel<256, 64><<<dim3(128, 1), dim3(256), 0, stream>>>(x1, W1, h1);
  sn_kernel<64><<<dim3(2048), dim3(256), 0, stream>>>(h1, as1, an1, s1, n1);
  split_kernel<64><<<dim3(256), dim3(256), 0, stream>>>(h1, Th1, Tl1);
  attn2_kernel<<<dim3(256), dim3(512), 0, stream>>>(Mm, Bm, s1, n1, Th1, Tl1, out);
}

// Round 5
// 464.399 us; speedup vs baseline: 2.4801x; 1.0041x over previous
//
#include <hip/hip_runtime.h>
#include <hip/hip_bf16.h>

constexpr int NN = 8192;
using uint = unsigned int;

typedef __bf16 bf16x8 __attribute__((ext_vector_type(8)));
typedef float f32x4 __attribute__((ext_vector_type(4)));
typedef float f32x16 __attribute__((ext_vector_type(16)));
typedef unsigned short ushort8_t __attribute__((ext_vector_type(8)));

__device__ __forceinline__ float eluf(float z) { return z > 0.f ? z : __expf(z) - 1.f; }

__device__ __forceinline__ unsigned short bf16_hi(float v) {
  unsigned u = __float_as_uint(v);
  unsigned r = u + 0x7fffu + ((u >> 16) & 1u);
  return (unsigned short)(r >> 16);
}
__device__ __forceinline__ float bf16_tof(unsigned short u) {
  return __uint_as_float(((unsigned)u) << 16);
}

// LDS-only barrier: order LDS ops across the barrier WITHOUT draining vmcnt.
// (__syncthreads would emit s_waitcnt vmcnt(0) and kill the global prefetch.)
__device__ __forceinline__ void lds_barrier() {
  asm volatile("s_waitcnt lgkmcnt(0)" ::: "memory");
  __builtin_amdgcn_s_barrier();
}

// ---------------------------------------------------------------------------
// GEMM: C[M][NOUT] = A[M][K] @ W[K][NOUT]   (fp32, BM=64,BN=64,BK=16, 4x4 micro)
// ---------------------------------------------------------------------------
template<int K, int NOUT>
__global__ __launch_bounds__(256) void gemm_kernel(
    const float* __restrict__ A, const float* __restrict__ W, float* __restrict__ C) {
  constexpr int BM = 64, BN = 64, BK = 16;
  __shared__ __align__(16) float As[BK][BM + 4];
  __shared__ __align__(16) float Ws[BK][BN];
  const int t = threadIdx.x;
  const int i0 = blockIdx.x * BM;
  const int c0 = blockIdx.y * BN;
  const int tr = t >> 4;
  const int tc = t & 15;
  const int lr = t >> 2;
  const int lk = (t & 3) * 4;
  const int wk = t >> 4;
  const int wc = (t & 15) * 4;
  float acc[4][4] = {};
  for (int k0 = 0; k0 < K; k0 += BK) {
    const float4 a4 = *reinterpret_cast<const float4*>(&A[(size_t)(i0 + lr) * K + k0 + lk]);
    As[lk + 0][lr] = a4.x; As[lk + 1][lr] = a4.y;
    As[lk + 2][lr] = a4.z; As[lk + 3][lr] = a4.w;
    *reinterpret_cast<float4*>(&Ws[wk][wc]) =
        *reinterpret_cast<const float4*>(&W[(size_t)(k0 + wk) * NOUT + c0 + wc]);
    __syncthreads();
    #pragma unroll
    for (int kk = 0; kk < BK; ++kk) {
      const float4 av = *reinterpret_cast<const float4*>(&As[kk][4 * tr]);
      const float4 wv = *reinterpret_cast<const float4*>(&Ws[kk][4 * tc]);
      const float a[4] = {av.x, av.y, av.z, av.w};
      const float w[4] = {wv.x, wv.y, wv.z, wv.w};
      #pragma unroll
      for (int i = 0; i < 4; ++i)
        #pragma unroll
        for (int j = 0; j < 4; ++j) acc[i][j] += a[i] * w[j];
    }
    __syncthreads();
  }
  #pragma unroll
  for (int i = 0; i < 4; ++i) {
    const float4 o = make_float4(acc[i][0], acc[i][1], acc[i][2], acc[i][3]);
    *reinterpret_cast<float4*>(&C[(size_t)(i0 + 4 * tr + i) * NOUT + c0 + 4 * tc]) = o;
  }
}

// ---------------------------------------------------------------------------
// s[i] = h[i].a_self ; n[i] = h[i].a_neigh   (one wave per row)
// ---------------------------------------------------------------------------
template<int FOUT>
__global__ __launch_bounds__(256) void sn_kernel(
    const float* __restrict__ H, const float* __restrict__ a_self,
    const float* __restrict__ a_neigh, float* __restrict__ s, float* __restrict__ n) {
  const int wave = threadIdx.x >> 6;
  const int lane = threadIdx.x & 63;
  const int row = blockIdx.x * 4 + wave;
  float ds = 0.f, dn = 0.f;
  #pragma unroll
  for (int c = lane; c < FOUT; c += 64) {
    const float h = H[(size_t)row * FOUT + c];
    ds += h * a_self[c];
    dn += h * a_neigh[c];
  }
  #pragma unroll
  for (int off = 32; off > 0; off >>= 1) {
    ds += __shfl_down(ds, off);
    dn += __shfl_down(dn, off);
  }
  if (lane == 0) { s[row] = ds; n[row] = dn; }
}

// ---------------------------------------------------------------------------
// Split H (fp32 [N][F]) into hi/lo bf16 in MFMA-staging layout:
//   T[tile=j/32][kc8=0..3][col=0..F-1][e=0..7]  (element j = tile*32+kc8*8+e)
// ---------------------------------------------------------------------------
template<int F>
__global__ __launch_bounds__(256) void split_kernel(
    const float* __restrict__ H, unsigned short* __restrict__ Th,
    unsigned short* __restrict__ Tl) {
  const int t = threadIdx.x;
  const int tile = blockIdx.x;
  const int c = t & (F - 1);
  const int kcb = t / F;
  for (int kc = kcb; kc < 4; kc += 256 / F) {
    ushort8_t hi, lo;
    #pragma unroll
    for (int e = 0; e < 8; ++e) {
      float v = H[(size_t)(tile * 32 + kc * 8 + e) * F + c];
      unsigned short h = bf16_hi(v);
      hi[e] = h;
      lo[e] = bf16_hi(v - bf16_tof(h));
    }
    size_t o = ((size_t)(tile * 4 + kc) * F + c) * 8;
    *reinterpret_cast<ushort8_t*>(&Th[o]) = hi;
    *reinterpret_cast<ushort8_t*>(&Tl[o]) = lo;
  }
}

// ---------------------------------------------------------------------------
// adj (int32 0/1) -> bitmask, word W covers cols [W*32, W*32+32) of a row.
// ---------------------------------------------------------------------------
__global__ __launch_bounds__(256) void mask_kernel(
    const int* __restrict__ adj, uint* __restrict__ Bm) {
  const size_t tg = (size_t)blockIdx.x * 256 + threadIdx.x;
  const int4 a = *reinterpret_cast<const int4*>(&adj[tg * 4]);
  uint nib = (a.x > 0 ? 1u : 0u) | (a.y > 0 ? 2u : 0u) |
             (a.z > 0 ? 4u : 0u) | (a.w > 0 ? 8u : 0u);
  const int lane = threadIdx.x & 63;
  uint v = nib << ((lane & 7) * 4);
  v |= __shfl_xor(v, 1);
  v |= __shfl_xor(v, 2);
  v |= __shfl_xor(v, 4);
  if ((lane & 7) == 0) Bm[tg >> 3] = v;
}

// ---------------------------------------------------------------------------
// Layer-1 fused attention. F=256, BR=32, 512 thr (8 waves), one barrier/tile.
// Wave w = col-frag (32 cols), full K per wave via 2 sub-MFMAs (32x32x16).
// B-frags global->reg (L2-resident), prefetch 1 tile; M/mask prefetch 2 tiles.
// Per-tile barrier is lgkmcnt-only so global prefetches stay in flight.
// ---------------------------------------------------------------------------
__global__ __launch_bounds__(512) void attn1_kernel(
    const float* __restrict__ Mm, const uint* __restrict__ Bm,
    const float* __restrict__ sv, const float* __restrict__ nv,
    const unsigned short* __restrict__ Th, const unsigned short* __restrict__ Tl,
    float* __restrict__ out) {
  constexpr int F = 256, BR = 32, NT = NN / 32;
  __shared__ __align__(16) uint Pa[2][2][512];  // [buf][hi/lo][(kc8*32+row)*4+quad]
  __shared__ float nvs[NN];
  __shared__ float l_lds[BR];

  const int t = threadIdx.x;
  const int lane = t & 63;
  const int cf = t >> 6;             // wave = col-frag
  const int r = t >> 4;              // score row 0..31
  const int p2 = t & 15;             // col pair: cols 2p2, 2p2+1
  const int i0 = blockIdx.x * BR;

  for (int i = t; i < NN / 4; i += 512)
    reinterpret_cast<float4*>(nvs)[i] = reinterpret_cast<const float4*>(nv)[i];

  const float svr = sv[i0 + r];
  const size_t mrow = (size_t)(i0 + r) * NN;
  const uint* mkrow = Bm + (size_t)(i0 + r) * (NN / 32);
  const int col = cf * 32 + (lane & 31);
  const size_t bo0 = ((size_t)(lane >> 5) * F + col) * 8;  // kc8 in {0,1}; +4096 for {2,3}
  const int pidx = ((p2 >> 2) * 32 + r) * 4 + (p2 & 3);
  const int aidx = ((lane >> 5) * 32 + (lane & 31)) * 4;

  float2 M_e = *reinterpret_cast<const float2*>(&Mm[mrow + 2 * p2]);
  float2 M_o = *reinterpret_cast<const float2*>(&Mm[mrow + 32 + 2 * p2]);
  uint mk_e = mkrow[0];
  uint mk_o = mkrow[1];
  bf16x8 bh0_e = *reinterpret_cast<const bf16x8*>(Th + bo0);
  bf16x8 bl0_e = *reinterpret_cast<const bf16x8*>(Tl + bo0);
  bf16x8 bh1_e = *reinterpret_cast<const bf16x8*>(Th + bo0 + 4096);
  bf16x8 bl1_e = *reinterpret_cast<const bf16x8*>(Tl + bo0 + 4096);
  bf16x8 bh0_o, bl0_o, bh1_o, bl1_o;

  float rsum = 0.f;
  f32x16 acc;
  #pragma unroll
  for (int i = 0; i < 16; ++i) acc[i] = 0.f;

  __syncthreads();

#define STEP1(TJ, MC, MKC, BH0C, BL0C, BH1C, BL1C, BH0N, BL0N, BH1N, BL1N)        \
  {                                                                               \
    const int t_j = (TJ);                                                         \
    const int jb = (t_j + 1 < NT) ? t_j + 1 : 0;                                  \
    const size_t tb = (size_t)jb * 8192;                                          \
    BH0N = *reinterpret_cast<const bf16x8*>(Th + tb + bo0);                       \
    BL0N = *reinterpret_cast<const bf16x8*>(Tl + tb + bo0);                       \
    BH1N = *reinterpret_cast<const bf16x8*>(Th + tb + bo0 + 4096);                \
    BL1N = *reinterpret_cast<const bf16x8*>(Tl + tb + bo0 + 4096);                \
    const int jm = (t_j + 2 < NT) ? t_j + 2 : 0;                                  \
    const float2 Mnew = *reinterpret_cast<const float2*>(&Mm[mrow + (size_t)jm * 32 + 2 * p2]); \
    const uint mknew = mkrow[jm];                                                 \
    const float nv0 = nvs[t_j * 32 + 2 * p2];                                     \
    const float nv1 = nvs[t_j * 32 + 2 * p2 + 1];                                 \
    float e0 = (svr + nv0) * MC.x; e0 = fmaxf(e0, 0.2f * e0); e0 = fminf(e0, 70.f); \
    float e1 = (svr + nv1) * MC.y; e1 = fmaxf(e1, 0.2f * e1); e1 = fminf(e1, 70.f); \
    const float p0 = ((MKC >> (2 * p2)) & 1u) ? __expf(e0) : 0.f;                 \
    const float p1 = ((MKC >> (2 * p2 + 1)) & 1u) ? __expf(e1) : 0.f;             \
    rsum += p0 + p1;                                                              \
    const unsigned short h0 = bf16_hi(p0), h1 = bf16_hi(p1);                      \
    const uint hw = (uint)h0 | ((uint)h1 << 16);                                  \
    const uint lw = (uint)bf16_hi(p0 - bf16_tof(h0)) |                            \
                    ((uint)bf16_hi(p1 - bf16_tof(h1)) << 16);                     \
    Pa[t_j & 1][0][pidx] = hw;                                                    \
    Pa[t_j & 1][1][pidx] = lw;                                                    \
    MC = Mnew; MKC = mknew;                                                       \
    lds_barrier();                                                                \
    const uint* pb0 = &Pa[t_j & 1][0][0];                                         \
    const uint* pb1 = &Pa[t_j & 1][1][0];                                         \
    const bf16x8 ah0 = *reinterpret_cast<const bf16x8*>(&pb0[aidx]);              \
    const bf16x8 al0 = *reinterpret_cast<const bf16x8*>(&pb1[aidx]);              \
    const bf16x8 ah1 = *reinterpret_cast<const bf16x8*>(&pb0[aidx + 256]);        \
    const bf16x8 al1 = *reinterpret_cast<const bf16x8*>(&pb1[aidx + 256]);        \
    acc = __builtin_amdgcn_mfma_f32_32x32x16_bf16(al0, BH0C, acc, 0, 0, 0);       \
    acc = __builtin_amdgcn_mfma_f32_32x32x16_bf16(ah0, BL0C, acc, 0, 0, 0);       \
    acc = __builtin_amdgcn_mfma_f32_32x32x16_bf16(ah0, BH0C, acc, 0, 0, 0);       \
    acc = __builtin_amdgcn_mfma_f32_32x32x16_bf16(al1, BH1C, acc, 0, 0, 0);       \
    acc = __builtin_amdgcn_mfma_f32_32x32x16_bf16(ah1, BL1C, acc, 0, 0, 0);       \
    acc = __builtin_amdgcn_mfma_f32_32x32x16_bf16(ah1, BH1C, acc, 0, 0, 0);       \
  }

  for (int tj = 0; tj < NT; tj += 2) {
    STEP1(tj,     M_e, mk_e, bh0_e, bl0_e, bh1_e, bl1_e, bh0_o, bl0_o, bh1_o, bl1_o)
    STEP1(tj + 1, M_o, mk_o, bh0_o, bl0_o, bh1_o, bl1_o, bh0_e, bl0_e, bh1_e, bl1_e)
  }
#undef STEP1

  #pragma unroll
  for (int off = 1; off < 16; off <<= 1) rsum += __shfl_xor(rsum, off);
  if (p2 == 0) l_lds[r] = rsum;
  __syncthreads();

  #pragma unroll
  for (int reg = 0; reg < 16; ++reg) {
    const int row = (reg & 3) + 8 * (reg >> 2) + 4 * (lane >> 5);
    const float v = acc[reg] / l_lds[row];
    out[(size_t)(i0 + row) * F + col] = eluf(v);
  }
}

// ---------------------------------------------------------------------------
// Layer-2 fused attention. F=64, BR=32, 512 thr (8 waves): rb=w&1 (16-row
// frag), cf=w>>1 (16-col frag), mfma_f32_16x16x32_bf16, full K per wave.
// ---------------------------------------------------------------------------
__global__ __launch_bounds__(512) void attn2_kernel(
    const float* __restrict__ Mm, const uint* __restrict__ Bm,
    const float* __restrict__ sv, const float* __restrict__ nv,
    const unsigned short* __restrict__ Th, const unsigned short* __restrict__ Tl,
    float* __restrict__ out) {
  constexpr int F = 64, BR = 32, NT = NN / 32;
  __shared__ __align__(16) uint Pa[2][2][512];
  __shared__ float nvs[NN];
  __shared__ float l_lds[BR];

  const int t = threadIdx.x;
  const int lane = t & 63;
  const int w = t >> 6;
  const int rb = w & 1;
  const int cf = w >> 1;
  const int r = t >> 4;
  const int p2 = t & 15;
  const int i0 = blockIdx.x * BR;

  for (int i = t; i < NN / 4; i += 512)
    reinterpret_cast<float4*>(nvs)[i] = reinterpret_cast<const float4*>(nv)[i];

  const float svr = sv[i0 + r];
  const size_t mrow = (size_t)(i0 + r) * NN;
  const uint* mkrow = Bm + (size_t)(i0 + r) * (NN / 32);
  const int col = cf * 16 + (lane & 15);
  const size_t bo2 = ((size_t)(lane >> 4) * F + col) * 8;
  const int pidx = ((p2 >> 2) * 32 + r) * 4 + (p2 & 3);
  const int aidx = ((lane >> 4) * 32 + rb * 16 + (lane & 15)) * 4;

  float2 M_e = *reinterpret_cast<const float2*>(&Mm[mrow + 2 * p2]);
  float2 M_o = *reinterpret_cast<const float2*>(&Mm[mrow + 32 + 2 * p2]);
  uint mk_e = mkrow[0];
  uint mk_o = mkrow[1];
  bf16x8 bh_e = *reinterpret_cast<const bf16x8*>(Th + bo2);
  bf16x8 bl_e = *reinterpret_cast<const bf16x8*>(Tl + bo2);
  bf16x8 bh_o, bl_o;

  float rsum = 0.f;
  f32x4 acc = {0.f, 0.f, 0.f, 0.f};

  __syncthreads();

#define STEP2(TJ, MC, MKC, BHC, BLC, BHN, BLN)                                    \
  {                                                                               \
    const int t_j = (TJ);                                                         \
    const int jb = (t_j + 1 < NT) ? t_j + 1 : 0;                                  \
    const size_t tb = (size_t)jb * 2048;                                          \
    BHN = *reinterpret_cast<const bf16x8*>(Th + tb + bo2);                        \
    BLN = *reinterpret_cast<const bf16x8*>(Tl + tb + bo2);                        \
    const int jm = (t_j + 2 < NT) ? t_j + 2 : 0;                                  \
    const float2 Mnew = *reinterpret_cast<const float2*>(&Mm[mrow + (size_t)jm * 32 + 2 * p2]); \
    const uint mknew = mkrow[jm];                                                 \
    const float nv0 = nvs[t_j * 32 + 2 * p2];                                     \
    const float nv1 = nvs[t_j * 32 + 2 * p2 + 1];                                 \
    float e0 = (svr + nv0) * MC.x; e0 = fmaxf(e0, 0.2f * e0); e0 = fminf(e0, 70.f); \
    float e1 = (svr + nv1) * MC.y; e1 = fmaxf(e1, 0.2f * e1); e1 = fminf(e1, 70.f); \
    const float p0 = ((MKC >> (2 * p2)) & 1u) ? __expf(e0) : 0.f;                 \
    const float p1 = ((MKC >> (2 * p2 + 1)) & 1u) ? __expf(e1) : 0.f;             \
    rsum += p0 + p1;                                                              \
    const unsigned short h0 = bf16_hi(p0), h1 = bf16_hi(p1);                      \
    const uint hw = (uint)h0 | ((uint)h1 << 16);                                  \
    const uint lw = (uint)bf16_hi(p0 - bf16_tof(h0)) |                            \
                    ((uint)bf16_hi(p1 - bf16_tof(h1)) << 16);                     \
    Pa[t_j & 1][0][pidx] = hw;                                                    \
    Pa[t_j & 1][1][pidx] = lw;                                                    \
    MC = Mnew; MKC = mknew;                                                       \
    lds_barrier();                                                                \
    const bf16x8 ah = *reinterpret_cast<const bf16x8*>(&Pa[t_j & 1][0][aidx]);    \
    const bf16x8 al = *reinterpret_cast<const bf16x8*>(&Pa[t_j & 1][1][aidx]);    \
    acc = __builtin_amdgcn_mfma_f32_16x16x32_bf16(al, BHC, acc, 0, 0, 0);         \
    acc = __builtin_amdgcn_mfma_f32_16x16x32_bf16(ah, BLC, acc, 0, 0, 0);         \
    acc = __builtin_amdgcn_mfma_f32_16x16x32_bf16(ah, BHC, acc, 0, 0, 0);         \
  }

  for (int tj = 0; tj < NT; tj += 2) {
    STEP2(tj,     M_e, mk_e, bh_e, bl_e, bh_o, bl_o)
    STEP2(tj + 1, M_o, mk_o, bh_o, bl_o, bh_e, bl_e)
  }
#undef STEP2

  #pragma unroll
  for (int off = 1; off < 16; off <<= 1) rsum += __shfl_xor(rsum, off);
  if (p2 == 0) l_lds[r] = rsum;
  __syncthreads();

  #pragma unroll
  for (int reg = 0; reg < 4; ++reg) {
    const int row = rb * 16 + (lane >> 4) * 4 + reg;
    const float v = acc[reg] / l_lds[row];
    out[(size_t)(i0 + row) * F + col] = eluf(v);
  }
}

// ---------------------------------------------------------------------------
extern "C" void kernel_launch(void* const* d_in, const int* in_sizes, int n_in,
                              void* d_out, int out_size, void* d_ws, size_t ws_size,
                              hipStream_t stream) {
  const float* x   = (const float*)d_in[0];
  const int*   adj = (const int*)  d_in[1];
  const float* Mm  = (const float*)d_in[2];
  const float* W0  = (const float*)d_in[3];
  const float* as0 = (const float*)d_in[4];
  const float* an0 = (const float*)d_in[5];
  const float* W1  = (const float*)d_in[6];
  const float* as1 = (const float*)d_in[7];
  const float* an1 = (const float*)d_in[8];
  float* out = (float*)d_out;

  char* ws = (char*)d_ws;
  const size_t MB = 1048576;
  float* h0  = (float*)(ws);                              // 8 MB (dead after split1)
  uint*  Bm  = (uint*) (ws);                              // 8 MB (written after split1)
  float* x1  = (float*)(ws + 8 * MB);                     // 8 MB
  float* h1  = (float*)(ws + 16 * MB);                    // 2 MB
  unsigned short* Th0 = (unsigned short*)(ws + 18 * MB);  // 4 MB
  unsigned short* Tl0 = (unsigned short*)(ws + 22 * MB);  // 4 MB
  unsigned short* Th1 = (unsigned short*)(ws + 26 * MB);  // 1 MB
  unsigned short* Tl1 = (unsigned short*)(ws + 27 * MB);  // 1 MB
  float* s0 = (float*)(ws + 28 * MB);
  float* n0 = s0 + NN;
  float* s1 = n0 + NN;
  float* n1 = s1 + NN;

  // ---- layer 1 ----
  gemm_kernel<512, 256><<<dim3(128, 4), dim3(256), 0, stream>>>(x, W0, h0);
  sn_kernel<256><<<dim3(2048), dim3(256), 0, stream>>>(h0, as0, an0, s0, n0);
  split_kernel<256><<<dim3(256), dim3(256), 0, stream>>>(h0, Th0, Tl0);
  mask_kernel<<<dim3(65536), dim3(256), 0, stream>>>(adj, Bm);   // h0 now dead
  attn1_kernel<<<dim3(256), dim3(512), 0, stream>>>(Mm, Bm, s0, n0, Th0, Tl0, x1);
  // ---- layer 2 ----
  gemm_kernel<256, 64><<<dim3(128, 1), dim3(256), 0, stream>>>(x1, W1, h1);
  sn_kernel<64><<<dim3(2048), dim3(256), 0, stream>>>(h1, as1, an1, s1, n1);
  split_kernel<64><<<dim3(256), dim3(256), 0, stream>>>(h1, Th1, Tl1);
  attn2_kernel<<<dim3(256), dim3(512), 0, stream>>>(Mm, Bm, s1, n1, Th1, Tl1, out);
}

// Round 6
// 445.919 us; speedup vs baseline: 2.5829x; 1.0414x over previous
//
#include <hip/hip_runtime.h>
#include <hip/hip_bf16.h>

constexpr int NN = 8192;
using uint = unsigned int;

typedef __bf16 bf16x8 __attribute__((ext_vector_type(8)));
typedef float f32x4 __attribute__((ext_vector_type(4)));
typedef float f32x16 __attribute__((ext_vector_type(16)));
typedef unsigned short ushort8_t __attribute__((ext_vector_type(8)));

__device__ __forceinline__ float eluf(float z) { return z > 0.f ? z : __expf(z) - 1.f; }

__device__ __forceinline__ unsigned short bf16_hi(float v) {
  unsigned u = __float_as_uint(v);
  unsigned r = u + 0x7fffu + ((u >> 16) & 1u);
  return (unsigned short)(r >> 16);
}
__device__ __forceinline__ float bf16_tof(unsigned short u) {
  return __uint_as_float(((unsigned)u) << 16);
}

// LDS-only barrier: order LDS ops across the barrier WITHOUT draining vmcnt.
__device__ __forceinline__ void lds_barrier() {
  asm volatile("s_waitcnt lgkmcnt(0)" ::: "memory");
  __builtin_amdgcn_s_barrier();
}

// ---------------------------------------------------------------------------
// GEMM: C[M][NOUT] = A[M][K] @ W[K][NOUT]   (fp32, BM=64,BN=64,BK=16, 4x4 micro)
// ---------------------------------------------------------------------------
template<int K, int NOUT>
__global__ __launch_bounds__(256) void gemm_kernel(
    const float* __restrict__ A, const float* __restrict__ W, float* __restrict__ C) {
  constexpr int BM = 64, BN = 64, BK = 16;
  __shared__ __align__(16) float As[BK][BM + 4];
  __shared__ __align__(16) float Ws[BK][BN];
  const int t = threadIdx.x;
  const int i0 = blockIdx.x * BM;
  const int c0 = blockIdx.y * BN;
  const int tr = t >> 4;
  const int tc = t & 15;
  const int lr = t >> 2;
  const int lk = (t & 3) * 4;
  const int wk = t >> 4;
  const int wc = (t & 15) * 4;
  float acc[4][4] = {};
  for (int k0 = 0; k0 < K; k0 += BK) {
    const float4 a4 = *reinterpret_cast<const float4*>(&A[(size_t)(i0 + lr) * K + k0 + lk]);
    As[lk + 0][lr] = a4.x; As[lk + 1][lr] = a4.y;
    As[lk + 2][lr] = a4.z; As[lk + 3][lr] = a4.w;
    *reinterpret_cast<float4*>(&Ws[wk][wc]) =
        *reinterpret_cast<const float4*>(&W[(size_t)(k0 + wk) * NOUT + c0 + wc]);
    __syncthreads();
    #pragma unroll
    for (int kk = 0; kk < BK; ++kk) {
      const float4 av = *reinterpret_cast<const float4*>(&As[kk][4 * tr]);
      const float4 wv = *reinterpret_cast<const float4*>(&Ws[kk][4 * tc]);
      const float a[4] = {av.x, av.y, av.z, av.w};
      const float w[4] = {wv.x, wv.y, wv.z, wv.w};
      #pragma unroll
      for (int i = 0; i < 4; ++i)
        #pragma unroll
        for (int j = 0; j < 4; ++j) acc[i][j] += a[i] * w[j];
    }
    __syncthreads();
  }
  #pragma unroll
  for (int i = 0; i < 4; ++i) {
    const float4 o = make_float4(acc[i][0], acc[i][1], acc[i][2], acc[i][3]);
    *reinterpret_cast<float4*>(&C[(size_t)(i0 + 4 * tr + i) * NOUT + c0 + 4 * tc]) = o;
  }
}

// ---------------------------------------------------------------------------
// s[i] = h[i].a_self ; n[i] = h[i].a_neigh   (one wave per row)
// ---------------------------------------------------------------------------
template<int FOUT>
__global__ __launch_bounds__(256) void sn_kernel(
    const float* __restrict__ H, const float* __restrict__ a_self,
    const float* __restrict__ a_neigh, float* __restrict__ s, float* __restrict__ n) {
  const int wave = threadIdx.x >> 6;
  const int lane = threadIdx.x & 63;
  const int row = blockIdx.x * 4 + wave;
  float ds = 0.f, dn = 0.f;
  #pragma unroll
  for (int c = lane; c < FOUT; c += 64) {
    const float h = H[(size_t)row * FOUT + c];
    ds += h * a_self[c];
    dn += h * a_neigh[c];
  }
  #pragma unroll
  for (int off = 32; off > 0; off >>= 1) {
    ds += __shfl_down(ds, off);
    dn += __shfl_down(dn, off);
  }
  if (lane == 0) { s[row] = ds; n[row] = dn; }
}

// ---------------------------------------------------------------------------
// Split H (fp32 [N][F]) into hi/lo bf16 in MFMA-staging layout:
//   T[tile=j/32][kc8=0..3][col=0..F-1][e=0..7]  (element j = tile*32+kc8*8+e)
// ---------------------------------------------------------------------------
template<int F>
__global__ __launch_bounds__(256) void split_kernel(
    const float* __restrict__ H, unsigned short* __restrict__ Th,
    unsigned short* __restrict__ Tl) {
  const int t = threadIdx.x;
  const int tile = blockIdx.x;
  const int c = t & (F - 1);
  const int kcb = t / F;
  for (int kc = kcb; kc < 4; kc += 256 / F) {
    ushort8_t hi, lo;
    #pragma unroll
    for (int e = 0; e < 8; ++e) {
      float v = H[(size_t)(tile * 32 + kc * 8 + e) * F + c];
      unsigned short h = bf16_hi(v);
      hi[e] = h;
      lo[e] = bf16_hi(v - bf16_tof(h));
    }
    size_t o = ((size_t)(tile * 4 + kc) * F + c) * 8;
    *reinterpret_cast<ushort8_t*>(&Th[o]) = hi;
    *reinterpret_cast<ushort8_t*>(&Tl[o]) = lo;
  }
}

// ---------------------------------------------------------------------------
// adj (int32 0/1) -> bitmask, word W covers cols [W*32, W*32+32) of a row.
// ---------------------------------------------------------------------------
__global__ __launch_bounds__(256) void mask_kernel(
    const int* __restrict__ adj, uint* __restrict__ Bm) {
  const size_t tg = (size_t)blockIdx.x * 256 + threadIdx.x;
  const int4 a = *reinterpret_cast<const int4*>(&adj[tg * 4]);
  uint nib = (a.x > 0 ? 1u : 0u) | (a.y > 0 ? 2u : 0u) |
             (a.z > 0 ? 4u : 0u) | (a.w > 0 ? 8u : 0u);
  const int lane = threadIdx.x & 63;
  uint v = nib << ((lane & 7) * 4);
  v |= __shfl_xor(v, 1);
  v |= __shfl_xor(v, 2);
  v |= __shfl_xor(v, 4);
  if ((lane & 7) == 0) Bm[tg >> 3] = v;
}

// ---------------------------------------------------------------------------
// Layer-1 fused attention. F=256, BR=32, 512 thr (8 waves), one barrier/tile.
// Consume-then-refill prefetch: score kills M/mask/nv regs, then tile+2 loads
// are DIRECTLY assigned into them (no temp copy -> no in-order vmcnt stall;
// the wait attaches to the use 2 tiles later). B-frags 1 tile deep, same idea.
// ---------------------------------------------------------------------------
__global__ __launch_bounds__(512) void attn1_kernel(
    const float* __restrict__ Mm, const uint* __restrict__ Bm,
    const float* __restrict__ sv, const float* __restrict__ nv,
    const unsigned short* __restrict__ Th, const unsigned short* __restrict__ Tl,
    float* __restrict__ out) {
  constexpr int F = 256, BR = 32, NT = NN / 32;
  __shared__ __align__(16) uint Pa[2][2][512];  // [buf][hi/lo][(kc8*32+row)*4+quad]
  __shared__ __align__(16) float nvs[NN];
  __shared__ float l_lds[BR];

  const int t = threadIdx.x;
  const int lane = t & 63;
  const int cf = t >> 6;             // wave = col-frag
  const int r = t >> 4;              // score row 0..31
  const int p2 = t & 15;             // col pair: cols 2p2, 2p2+1
  const int i0 = blockIdx.x * BR;

  for (int i = t; i < NN / 4; i += 512)
    reinterpret_cast<float4*>(nvs)[i] = reinterpret_cast<const float4*>(nv)[i];

  const float svr = sv[i0 + r];
  const size_t mrow = (size_t)(i0 + r) * NN;
  const uint* mkrow = Bm + (size_t)(i0 + r) * (NN / 32);
  const int col = cf * 32 + (lane & 31);
  const size_t bo0 = ((size_t)(lane >> 5) * F + col) * 8;  // kc8 in {0,1}; +4096 for {2,3}
  const int pidx = ((p2 >> 2) * 32 + r) * 4 + (p2 & 3);
  const int aidx = ((lane >> 5) * 32 + (lane & 31)) * 4;

  float2 M_e = *reinterpret_cast<const float2*>(&Mm[mrow + 2 * p2]);
  float2 M_o = *reinterpret_cast<const float2*>(&Mm[mrow + 32 + 2 * p2]);
  uint mk_e = mkrow[0];
  uint mk_o = mkrow[1];
  bf16x8 bh0_e = *reinterpret_cast<const bf16x8*>(Th + bo0);
  bf16x8 bl0_e = *reinterpret_cast<const bf16x8*>(Tl + bo0);
  bf16x8 bh1_e = *reinterpret_cast<const bf16x8*>(Th + bo0 + 4096);
  bf16x8 bl1_e = *reinterpret_cast<const bf16x8*>(Tl + bo0 + 4096);
  bf16x8 bh0_o, bl0_o, bh1_o, bl1_o;

  float rsum = 0.f;
  f32x16 acc;
  #pragma unroll
  for (int i = 0; i < 16; ++i) acc[i] = 0.f;

  __syncthreads();   // nvs staged

  float2 nv_e = *reinterpret_cast<const float2*>(&nvs[0 * 32 + 2 * p2]);
  float2 nv_o = *reinterpret_cast<const float2*>(&nvs[1 * 32 + 2 * p2]);

#define STEP1(TJ, MC, MKC, NVC, BH0C, BL0C, BH1C, BL1C, BH0N, BL0N, BH1N, BL1N)   \
  {                                                                               \
    const int t_j = (TJ);                                                         \
    /* 1. next-tile B loads into dead parity regs */                              \
    const int jb = (t_j + 1 < NT) ? t_j + 1 : 0;                                  \
    const size_t tb = (size_t)jb * 8192;                                          \
    BH0N = *reinterpret_cast<const bf16x8*>(Th + tb + bo0);                       \
    BL0N = *reinterpret_cast<const bf16x8*>(Tl + tb + bo0);                       \
    BH1N = *reinterpret_cast<const bf16x8*>(Th + tb + bo0 + 4096);                \
    BL1N = *reinterpret_cast<const bf16x8*>(Tl + tb + bo0 + 4096);                \
    /* 2. score: consumes MC/MKC/NVC */                                           \
    float e0 = (svr + NVC.x) * MC.x; e0 = fmaxf(e0, 0.2f * e0); e0 = fminf(e0, 70.f); \
    float e1 = (svr + NVC.y) * MC.y; e1 = fmaxf(e1, 0.2f * e1); e1 = fminf(e1, 70.f); \
    const float p0 = ((MKC >> (2 * p2)) & 1u) ? __expf(e0) : 0.f;                 \
    const float p1 = ((MKC >> (2 * p2 + 1)) & 1u) ? __expf(e1) : 0.f;             \
    rsum += p0 + p1;                                                              \
    /* 3. refill tile+2 DIRECTLY into the dead regs (no copy) */                  \
    const int jm = (t_j + 2 < NT) ? t_j + 2 : 0;                                  \
    MC = *reinterpret_cast<const float2*>(&Mm[mrow + (size_t)jm * 32 + 2 * p2]);  \
    MKC = mkrow[jm];                                                              \
    NVC = *reinterpret_cast<const float2*>(&nvs[jm * 32 + 2 * p2]);               \
    /* 4. pack + P writes */                                                      \
    const unsigned short h0 = bf16_hi(p0), h1 = bf16_hi(p1);                      \
    const uint hw = (uint)h0 | ((uint)h1 << 16);                                  \
    const uint lw = (uint)bf16_hi(p0 - bf16_tof(h0)) |                            \
                    ((uint)bf16_hi(p1 - bf16_tof(h1)) << 16);                     \
    Pa[t_j & 1][0][pidx] = hw;                                                    \
    Pa[t_j & 1][1][pidx] = lw;                                                    \
    lds_barrier();                                                                \
    /* 5. MFMA */                                                                 \
    const uint* pb0 = &Pa[t_j & 1][0][0];                                         \
    const uint* pb1 = &Pa[t_j & 1][1][0];                                         \
    const bf16x8 ah0 = *reinterpret_cast<const bf16x8*>(&pb0[aidx]);              \
    const bf16x8 al0 = *reinterpret_cast<const bf16x8*>(&pb1[aidx]);              \
    const bf16x8 ah1 = *reinterpret_cast<const bf16x8*>(&pb0[aidx + 256]);        \
    const bf16x8 al1 = *reinterpret_cast<const bf16x8*>(&pb1[aidx + 256]);        \
    acc = __builtin_amdgcn_mfma_f32_32x32x16_bf16(al0, BH0C, acc, 0, 0, 0);       \
    acc = __builtin_amdgcn_mfma_f32_32x32x16_bf16(ah0, BL0C, acc, 0, 0, 0);       \
    acc = __builtin_amdgcn_mfma_f32_32x32x16_bf16(ah0, BH0C, acc, 0, 0, 0);       \
    acc = __builtin_amdgcn_mfma_f32_32x32x16_bf16(al1, BH1C, acc, 0, 0, 0);       \
    acc = __builtin_amdgcn_mfma_f32_32x32x16_bf16(ah1, BL1C, acc, 0, 0, 0);       \
    acc = __builtin_amdgcn_mfma_f32_32x32x16_bf16(ah1, BH1C, acc, 0, 0, 0);       \
  }

  for (int tj = 0; tj < NT; tj += 2) {
    STEP1(tj,     M_e, mk_e, nv_e, bh0_e, bl0_e, bh1_e, bl1_e, bh0_o, bl0_o, bh1_o, bl1_o)
    STEP1(tj + 1, M_o, mk_o, nv_o, bh0_o, bl0_o, bh1_o, bl1_o, bh0_e, bl0_e, bh1_e, bl1_e)
  }
#undef STEP1

  #pragma unroll
  for (int off = 1; off < 16; off <<= 1) rsum += __shfl_xor(rsum, off);
  if (p2 == 0) l_lds[r] = rsum;
  __syncthreads();

  #pragma unroll
  for (int reg = 0; reg < 16; ++reg) {
    const int row = (reg & 3) + 8 * (reg >> 2) + 4 * (lane >> 5);
    const float v = acc[reg] / l_lds[row];
    out[(size_t)(i0 + row) * F + col] = eluf(v);
  }
}

// ---------------------------------------------------------------------------
// Layer-2 fused attention. F=64, BR=32, 512 thr (8 waves): rb=w&1 (16-row
// frag), cf=w>>1 (16-col frag), mfma_f32_16x16x32_bf16, full K per wave.
// Same consume-then-refill prefetch structure as attn1.
// ---------------------------------------------------------------------------
__global__ __launch_bounds__(512) void attn2_kernel(
    const float* __restrict__ Mm, const uint* __restrict__ Bm,
    const float* __restrict__ sv, const float* __restrict__ nv,
    const unsigned short* __restrict__ Th, const unsigned short* __restrict__ Tl,
    float* __restrict__ out) {
  constexpr int F = 64, BR = 32, NT = NN / 32;
  __shared__ __align__(16) uint Pa[2][2][512];
  __shared__ __align__(16) float nvs[NN];
  __shared__ float l_lds[BR];

  const int t = threadIdx.x;
  const int lane = t & 63;
  const int w = t >> 6;
  const int rb = w & 1;
  const int cf = w >> 1;
  const int r = t >> 4;
  const int p2 = t & 15;
  const int i0 = blockIdx.x * BR;

  for (int i = t; i < NN / 4; i += 512)
    reinterpret_cast<float4*>(nvs)[i] = reinterpret_cast<const float4*>(nv)[i];

  const float svr = sv[i0 + r];
  const size_t mrow = (size_t)(i0 + r) * NN;
  const uint* mkrow = Bm + (size_t)(i0 + r) * (NN / 32);
  const int col = cf * 16 + (lane & 15);
  const size_t bo2 = ((size_t)(lane >> 4) * F + col) * 8;
  const int pidx = ((p2 >> 2) * 32 + r) * 4 + (p2 & 3);
  const int aidx = ((lane >> 4) * 32 + rb * 16 + (lane & 15)) * 4;

  float2 M_e = *reinterpret_cast<const float2*>(&Mm[mrow + 2 * p2]);
  float2 M_o = *reinterpret_cast<const float2*>(&Mm[mrow + 32 + 2 * p2]);
  uint mk_e = mkrow[0];
  uint mk_o = mkrow[1];
  bf16x8 bh_e = *reinterpret_cast<const bf16x8*>(Th + bo2);
  bf16x8 bl_e = *reinterpret_cast<const bf16x8*>(Tl + bo2);
  bf16x8 bh_o, bl_o;

  float rsum = 0.f;
  f32x4 acc = {0.f, 0.f, 0.f, 0.f};

  __syncthreads();   // nvs staged

  float2 nv_e = *reinterpret_cast<const float2*>(&nvs[0 * 32 + 2 * p2]);
  float2 nv_o = *reinterpret_cast<const float2*>(&nvs[1 * 32 + 2 * p2]);

#define STEP2(TJ, MC, MKC, NVC, BHC, BLC, BHN, BLN)                               \
  {                                                                               \
    const int t_j = (TJ);                                                         \
    const int jb = (t_j + 1 < NT) ? t_j + 1 : 0;                                  \
    const size_t tb = (size_t)jb * 2048;                                          \
    BHN = *reinterpret_cast<const bf16x8*>(Th + tb + bo2);                        \
    BLN = *reinterpret_cast<const bf16x8*>(Tl + tb + bo2);                        \
    float e0 = (svr + NVC.x) * MC.x; e0 = fmaxf(e0, 0.2f * e0); e0 = fminf(e0, 70.f); \
    float e1 = (svr + NVC.y) * MC.y; e1 = fmaxf(e1, 0.2f * e1); e1 = fminf(e1, 70.f); \
    const float p0 = ((MKC >> (2 * p2)) & 1u) ? __expf(e0) : 0.f;                 \
    const float p1 = ((MKC >> (2 * p2 + 1)) & 1u) ? __expf(e1) : 0.f;             \
    rsum += p0 + p1;                                                              \
    const int jm = (t_j + 2 < NT) ? t_j + 2 : 0;                                  \
    MC = *reinterpret_cast<const float2*>(&Mm[mrow + (size_t)jm * 32 + 2 * p2]);  \
    MKC = mkrow[jm];                                                              \
    NVC = *reinterpret_cast<const float2*>(&nvs[jm * 32 + 2 * p2]);               \
    const unsigned short h0 = bf16_hi(p0), h1 = bf16_hi(p1);                      \
    const uint hw = (uint)h0 | ((uint)h1 << 16);                                  \
    const uint lw = (uint)bf16_hi(p0 - bf16_tof(h0)) |                            \
                    ((uint)bf16_hi(p1 - bf16_tof(h1)) << 16);                     \
    Pa[t_j & 1][0][pidx] = hw;                                                    \
    Pa[t_j & 1][1][pidx] = lw;                                                    \
    lds_barrier();                                                                \
    const bf16x8 ah = *reinterpret_cast<const bf16x8*>(&Pa[t_j & 1][0][aidx]);    \
    const bf16x8 al = *reinterpret_cast<const bf16x8*>(&Pa[t_j & 1][1][aidx]);    \
    acc = __builtin_amdgcn_mfma_f32_16x16x32_bf16(al, BHC, acc, 0, 0, 0);         \
    acc = __builtin_amdgcn_mfma_f32_16x16x32_bf16(ah, BLC, acc, 0, 0, 0);         \
    acc = __builtin_amdgcn_mfma_f32_16x16x32_bf16(ah, BHC, acc, 0, 0, 0);         \
  }

  for (int tj = 0; tj < NT; tj += 2) {
    STEP2(tj,     M_e, mk_e, nv_e, bh_e, bl_e, bh_o, bl_o)
    STEP2(tj + 1, M_o, mk_o, nv_o, bh_o, bl_o, bh_e, bl_e)
  }
#undef STEP2

  #pragma unroll
  for (int off = 1; off < 16; off <<= 1) rsum += __shfl_xor(rsum, off);
  if (p2 == 0) l_lds[r] = rsum;
  __syncthreads();

  #pragma unroll
  for (int reg = 0; reg < 4; ++reg) {
    const int row = rb * 16 + (lane >> 4) * 4 + reg;
    const float v = acc[reg] / l_lds[row];
    out[(size_t)(i0 + row) * F + col] = eluf(v);
  }
}

// ---------------------------------------------------------------------------
extern "C" void kernel_launch(void* const* d_in, const int* in_sizes, int n_in,
                              void* d_out, int out_size, void* d_ws, size_t ws_size,
                              hipStream_t stream) {
  const float* x   = (const float*)d_in[0];
  const int*   adj = (const int*)  d_in[1];
  const float* Mm  = (const float*)d_in[2];
  const float* W0  = (const float*)d_in[3];
  const float* as0 = (const float*)d_in[4];
  const float* an0 = (const float*)d_in[5];
  const float* W1  = (const float*)d_in[6];
  const float* as1 = (const float*)d_in[7];
  const float* an1 = (const float*)d_in[8];
  float* out = (float*)d_out;

  char* ws = (char*)d_ws;
  const size_t MB = 1048576;
  float* h0  = (float*)(ws);                              // 8 MB (dead after split1)
  uint*  Bm  = (uint*) (ws);                              // 8 MB (written after split1)
  float* x1  = (float*)(ws + 8 * MB);                     // 8 MB
  float* h1  = (float*)(ws + 16 * MB);                    // 2 MB
  unsigned short* Th0 = (unsigned short*)(ws + 18 * MB);  // 4 MB
  unsigned short* Tl0 = (unsigned short*)(ws + 22 * MB);  // 4 MB
  unsigned short* Th1 = (unsigned short*)(ws + 26 * MB);  // 1 MB
  unsigned short* Tl1 = (unsigned short*)(ws + 27 * MB);  // 1 MB
  float* s0 = (float*)(ws + 28 * MB);
  float* n0 = s0 + NN;
  float* s1 = n0 + NN;
  float* n1 = s1 + NN;

  // ---- layer 1 ----
  gemm_kernel<512, 256><<<dim3(128, 4), dim3(256), 0, stream>>>(x, W0, h0);
  sn_kernel<256><<<dim3(2048), dim3(256), 0, stream>>>(h0, as0, an0, s0, n0);
  split_kernel<256><<<dim3(256), dim3(256), 0, stream>>>(h0, Th0, Tl0);
  mask_kernel<<<dim3(65536), dim3(256), 0, stream>>>(adj, Bm);   // h0 now dead
  attn1_kernel<<<dim3(256), dim3(512), 0, stream>>>(Mm, Bm, s0, n0, Th0, Tl0, x1);
  // ---- layer 2 ----
  gemm_kernel<256, 64><<<dim3(128, 1), dim3(256), 0, stream>>>(x1, W1, h1);
  sn_kernel<64><<<dim3(2048), dim3(256), 0, stream>>>(h1, as1, an1, s1, n1);
  split_kernel<64><<<dim3(256), dim3(256), 0, stream>>>(h1, Th1, Tl1);
  attn2_kernel<<<dim3(256), dim3(512), 0, stream>>>(Mm, Bm, s1, n1, Th1, Tl1, out);
}

// Round 7
// 400.307 us; speedup vs baseline: 2.8772x; 1.1139x over previous
//
#include <hip/hip_runtime.h>
#include <hip/hip_bf16.h>

constexpr int NN = 8192;
using uint = unsigned int;

typedef __bf16 bf16x8 __attribute__((ext_vector_type(8)));
typedef float f32x4 __attribute__((ext_vector_type(4)));
typedef float f32x16 __attribute__((ext_vector_type(16)));
typedef unsigned short ushort8_t __attribute__((ext_vector_type(8)));

__device__ __forceinline__ float eluf(float z) { return z > 0.f ? z : __expf(z) - 1.f; }

__device__ __forceinline__ unsigned short bf16_hi(float v) {
  unsigned u = __float_as_uint(v);
  unsigned r = u + 0x7fffu + ((u >> 16) & 1u);
  return (unsigned short)(r >> 16);
}
__device__ __forceinline__ float bf16_tof(unsigned short u) {
  return __uint_as_float(((unsigned)u) << 16);
}

// LDS-only barrier: order LDS ops across the barrier WITHOUT draining vmcnt.
__device__ __forceinline__ void lds_barrier() {
  asm volatile("s_waitcnt lgkmcnt(0)" ::: "memory");
  __builtin_amdgcn_s_barrier();
}

// ---------------------------------------------------------------------------
// GEMM: C[M][NOUT] = A[M][K] @ W[K][NOUT]   (fp32, BM=64,BN=64,BK=16, 4x4 micro)
// ---------------------------------------------------------------------------
template<int K, int NOUT>
__global__ __launch_bounds__(256) void gemm_kernel(
    const float* __restrict__ A, const float* __restrict__ W, float* __restrict__ C) {
  constexpr int BM = 64, BN = 64, BK = 16;
  __shared__ __align__(16) float As[BK][BM + 4];
  __shared__ __align__(16) float Ws[BK][BN];
  const int t = threadIdx.x;
  const int i0 = blockIdx.x * BM;
  const int c0 = blockIdx.y * BN;
  const int tr = t >> 4;
  const int tc = t & 15;
  const int lr = t >> 2;
  const int lk = (t & 3) * 4;
  const int wk = t >> 4;
  const int wc = (t & 15) * 4;
  float acc[4][4] = {};
  for (int k0 = 0; k0 < K; k0 += BK) {
    const float4 a4 = *reinterpret_cast<const float4*>(&A[(size_t)(i0 + lr) * K + k0 + lk]);
    As[lk + 0][lr] = a4.x; As[lk + 1][lr] = a4.y;
    As[lk + 2][lr] = a4.z; As[lk + 3][lr] = a4.w;
    *reinterpret_cast<float4*>(&Ws[wk][wc]) =
        *reinterpret_cast<const float4*>(&W[(size_t)(k0 + wk) * NOUT + c0 + wc]);
    __syncthreads();
    #pragma unroll
    for (int kk = 0; kk < BK; ++kk) {
      const float4 av = *reinterpret_cast<const float4*>(&As[kk][4 * tr]);
      const float4 wv = *reinterpret_cast<const float4*>(&Ws[kk][4 * tc]);
      const float a[4] = {av.x, av.y, av.z, av.w};
      const float w[4] = {wv.x, wv.y, wv.z, wv.w};
      #pragma unroll
      for (int i = 0; i < 4; ++i)
        #pragma unroll
        for (int j = 0; j < 4; ++j) acc[i][j] += a[i] * w[j];
    }
    __syncthreads();
  }
  #pragma unroll
  for (int i = 0; i < 4; ++i) {
    const float4 o = make_float4(acc[i][0], acc[i][1], acc[i][2], acc[i][3]);
    *reinterpret_cast<float4*>(&C[(size_t)(i0 + 4 * tr + i) * NOUT + c0 + 4 * tc]) = o;
  }
}

// ---------------------------------------------------------------------------
// s[i] = h[i].a_self ; n[i] = h[i].a_neigh   (one wave per row)
// ---------------------------------------------------------------------------
template<int FOUT>
__global__ __launch_bounds__(256) void sn_kernel(
    const float* __restrict__ H, const float* __restrict__ a_self,
    const float* __restrict__ a_neigh, float* __restrict__ s, float* __restrict__ n) {
  const int wave = threadIdx.x >> 6;
  const int lane = threadIdx.x & 63;
  const int row = blockIdx.x * 4 + wave;
  float ds = 0.f, dn = 0.f;
  #pragma unroll
  for (int c = lane; c < FOUT; c += 64) {
    const float h = H[(size_t)row * FOUT + c];
    ds += h * a_self[c];
    dn += h * a_neigh[c];
  }
  #pragma unroll
  for (int off = 32; off > 0; off >>= 1) {
    ds += __shfl_down(ds, off);
    dn += __shfl_down(dn, off);
  }
  if (lane == 0) { s[row] = ds; n[row] = dn; }
}

// ---------------------------------------------------------------------------
// Split H (fp32 [N][F]) into hi/lo bf16 in MFMA-staging layout:
//   T[tile=j/32][kc8=0..3][col=0..F-1][e=0..7]  (element j = tile*32+kc8*8+e)
// ---------------------------------------------------------------------------
template<int F>
__global__ __launch_bounds__(256) void split_kernel(
    const float* __restrict__ H, unsigned short* __restrict__ Th,
    unsigned short* __restrict__ Tl) {
  const int t = threadIdx.x;
  const int tile = blockIdx.x;
  const int c = t & (F - 1);
  const int kcb = t / F;
  for (int kc = kcb; kc < 4; kc += 256 / F) {
    ushort8_t hi, lo;
    #pragma unroll
    for (int e = 0; e < 8; ++e) {
      float v = H[(size_t)(tile * 32 + kc * 8 + e) * F + c];
      unsigned short h = bf16_hi(v);
      hi[e] = h;
      lo[e] = bf16_hi(v - bf16_tof(h));
    }
    size_t o = ((size_t)(tile * 4 + kc) * F + c) * 8;
    *reinterpret_cast<ushort8_t*>(&Th[o]) = hi;
    *reinterpret_cast<ushort8_t*>(&Tl[o]) = lo;
  }
}

// ---------------------------------------------------------------------------
// adj (int32 0/1) -> bitmask, word W covers cols [W*32, W*32+32) of a row.
// ---------------------------------------------------------------------------
__global__ __launch_bounds__(256) void mask_kernel(
    const int* __restrict__ adj, uint* __restrict__ Bm) {
  const size_t tg = (size_t)blockIdx.x * 256 + threadIdx.x;
  const int4 a = *reinterpret_cast<const int4*>(&adj[tg * 4]);
  uint nib = (a.x > 0 ? 1u : 0u) | (a.y > 0 ? 2u : 0u) |
             (a.z > 0 ? 4u : 0u) | (a.w > 0 ? 8u : 0u);
  const int lane = threadIdx.x & 63;
  uint v = nib << ((lane & 7) * 4);
  v |= __shfl_xor(v, 1);
  v |= __shfl_xor(v, 2);
  v |= __shfl_xor(v, 4);
  if ((lane & 7) == 0) Bm[tg >> 3] = v;
}

// ---------------------------------------------------------------------------
// Layer-1 fused attention. F=256, BR=32, 1024 thr (16 waves), BC=64 k-tiles.
// Wave w: cf = w&7 (32-col frag), ks = w>>3 (k-half of 64). Per tile each wave
// does 6 MFMAs over its 32-k half; k-halves summed via LDS scratch at end.
// Score: thread handles cols 2p2,2p2+1 (p2=t&31) of row r=t>>5.
// Consume-then-refill M/mask/nv prefetch 2 tiles deep; B-frags 1 tile deep.
// ---------------------------------------------------------------------------
__global__ __launch_bounds__(1024, 4) void attn1_kernel(
    const float* __restrict__ Mm, const uint* __restrict__ Bm,
    const float* __restrict__ sv, const float* __restrict__ nv,
    const unsigned short* __restrict__ Th, const unsigned short* __restrict__ Tl,
    float* __restrict__ out) {
  constexpr int F = 256, BR = 32, NT = NN / 64;
  __shared__ __align__(16) uint Pa[2][2][1024];  // [buf][hi/lo][(kc8*32+row)*4+quad]
  __shared__ __align__(16) float nvs[NN];        // also reused as k-reduce scratch
  __shared__ float l_lds[BR];

  const int t = threadIdx.x;
  const int lane = t & 63;
  const int w = t >> 6;              // 0..15
  const int cf = w & 7;              // col-frag (32 cols)
  const int ks = w >> 3;             // k-half
  const int r = t >> 5;              // score row 0..31
  const int p2 = t & 31;             // col pair: cols 2p2, 2p2+1 (of 64)
  const int i0 = blockIdx.x * BR;

  for (int i = t; i < NN / 4; i += 1024)
    reinterpret_cast<float4*>(nvs)[i] = reinterpret_cast<const float4*>(nv)[i];

  const float svr = sv[i0 + r];
  const size_t mrow = (size_t)(i0 + r) * NN;
  const uint* mkrow = Bm + (size_t)(i0 + r) * (NN / 32);
  const int col = cf * 32 + (lane & 31);
  const size_t bo0 = ((size_t)(lane >> 5) * F + col) * 8;  // kc8 {0,1}; +4096 for {2,3}
  const int pidx = ((p2 >> 2) * 32 + r) * 4 + (p2 & 3);
  const int aidx = ((ks * 4 + (lane >> 5)) * 32 + (lane & 31)) * 4;

  float2 M_e = *reinterpret_cast<const float2*>(&Mm[mrow + 2 * p2]);
  float2 M_o = *reinterpret_cast<const float2*>(&Mm[mrow + 64 + 2 * p2]);
  uint mk_e = mkrow[0 + (p2 >> 4)];
  uint mk_o = mkrow[2 + (p2 >> 4)];
  const size_t tb0 = (size_t)ks * 8192;   // 32-row B-tile index = 2*0+ks
  bf16x8 bh0_e = *reinterpret_cast<const bf16x8*>(Th + tb0 + bo0);
  bf16x8 bl0_e = *reinterpret_cast<const bf16x8*>(Tl + tb0 + bo0);
  bf16x8 bh1_e = *reinterpret_cast<const bf16x8*>(Th + tb0 + bo0 + 4096);
  bf16x8 bl1_e = *reinterpret_cast<const bf16x8*>(Tl + tb0 + bo0 + 4096);
  bf16x8 bh0_o, bl0_o, bh1_o, bl1_o;

  float rsum = 0.f;
  f32x16 acc;
  #pragma unroll
  for (int i = 0; i < 16; ++i) acc[i] = 0.f;

  __syncthreads();   // nvs staged

  float2 nv_e = *reinterpret_cast<const float2*>(&nvs[2 * p2]);
  float2 nv_o = *reinterpret_cast<const float2*>(&nvs[64 + 2 * p2]);

#define STEP1(TJ, MC, MKC, NVC, BH0C, BL0C, BH1C, BL1C, BH0N, BL0N, BH1N, BL1N)   \
  {                                                                               \
    const int t_j = (TJ);                                                         \
    /* 1. next-tile B loads into dead parity regs */                              \
    const int jb = (t_j + 1 < NT) ? t_j + 1 : 0;                                  \
    const size_t tb = (size_t)(2 * jb + ks) * 8192;                               \
    BH0N = *reinterpret_cast<const bf16x8*>(Th + tb + bo0);                       \
    BL0N = *reinterpret_cast<const bf16x8*>(Tl + tb + bo0);                       \
    BH1N = *reinterpret_cast<const bf16x8*>(Th + tb + bo0 + 4096);                \
    BL1N = *reinterpret_cast<const bf16x8*>(Tl + tb + bo0 + 4096);                \
    /* 2. score: consumes MC/MKC/NVC */                                           \
    float e0 = (svr + NVC.x) * MC.x; e0 = fmaxf(e0, 0.2f * e0); e0 = fminf(e0, 70.f); \
    float e1 = (svr + NVC.y) * MC.y; e1 = fmaxf(e1, 0.2f * e1); e1 = fminf(e1, 70.f); \
    const float p0 = ((MKC >> (2 * (p2 & 15))) & 1u) ? __expf(e0) : 0.f;          \
    const float p1 = ((MKC >> (2 * (p2 & 15) + 1)) & 1u) ? __expf(e1) : 0.f;      \
    rsum += p0 + p1;                                                              \
    /* 3. refill tile+2 DIRECTLY into the dead regs (no copy) */                  \
    const int jm = (t_j + 2 < NT) ? t_j + 2 : 0;                                  \
    MC = *reinterpret_cast<const float2*>(&Mm[mrow + (size_t)jm * 64 + 2 * p2]);  \
    MKC = mkrow[jm * 2 + (p2 >> 4)];                                              \
    NVC = *reinterpret_cast<const float2*>(&nvs[jm * 64 + 2 * p2]);               \
    /* 4. pack + P writes */                                                      \
    const unsigned short h0 = bf16_hi(p0), h1 = bf16_hi(p1);                      \
    const uint hw = (uint)h0 | ((uint)h1 << 16);                                  \
    const uint lw = (uint)bf16_hi(p0 - bf16_tof(h0)) |                            \
                    ((uint)bf16_hi(p1 - bf16_tof(h1)) << 16);                     \
    Pa[t_j & 1][0][pidx] = hw;                                                    \
    Pa[t_j & 1][1][pidx] = lw;                                                    \
    lds_barrier();                                                                \
    /* 5. MFMA over this wave's 32-k half */                                      \
    const uint* pb0 = &Pa[t_j & 1][0][0];                                         \
    const uint* pb1 = &Pa[t_j & 1][1][0];                                         \
    const bf16x8 ah0 = *reinterpret_cast<const bf16x8*>(&pb0[aidx]);              \
    const bf16x8 al0 = *reinterpret_cast<const bf16x8*>(&pb1[aidx]);              \
    const bf16x8 ah1 = *reinterpret_cast<const bf16x8*>(&pb0[aidx + 256]);        \
    const bf16x8 al1 = *reinterpret_cast<const bf16x8*>(&pb1[aidx + 256]);        \
    acc = __builtin_amdgcn_mfma_f32_32x32x16_bf16(al0, BH0C, acc, 0, 0, 0);       \
    acc = __builtin_amdgcn_mfma_f32_32x32x16_bf16(ah0, BL0C, acc, 0, 0, 0);       \
    acc = __builtin_amdgcn_mfma_f32_32x32x16_bf16(ah0, BH0C, acc, 0, 0, 0);       \
    acc = __builtin_amdgcn_mfma_f32_32x32x16_bf16(al1, BH1C, acc, 0, 0, 0);       \
    acc = __builtin_amdgcn_mfma_f32_32x32x16_bf16(ah1, BL1C, acc, 0, 0, 0);       \
    acc = __builtin_amdgcn_mfma_f32_32x32x16_bf16(ah1, BH1C, acc, 0, 0, 0);       \
  }

  for (int tj = 0; tj < NT; tj += 2) {
    STEP1(tj,     M_e, mk_e, nv_e, bh0_e, bl0_e, bh1_e, bl1_e, bh0_o, bl0_o, bh1_o, bl1_o)
    STEP1(tj + 1, M_o, mk_o, nv_o, bh0_o, bl0_o, bh1_o, bl1_o, bh0_e, bl0_e, bh1_e, bl1_e)
  }
#undef STEP1

  // rowsum over the 32 threads of each row
  #pragma unroll
  for (int off = 1; off < 32; off <<= 1) rsum += __shfl_xor(rsum, off);
  if (p2 == 0) l_lds[r] = rsum;
  __syncthreads();   // all score reads of nvs done; l_lds visible

  // k-half reduction through LDS (reuse nvs as scratch: 8 cf * 1024 floats)
  float* scratch = nvs;
  if (ks == 1) {
    #pragma unroll
    for (int reg = 0; reg < 16; ++reg) scratch[cf * 1024 + reg * 64 + lane] = acc[reg];
  }
  __syncthreads();
  if (ks == 0) {
    #pragma unroll
    for (int reg = 0; reg < 16; ++reg) {
      const int row = (reg & 3) + 8 * (reg >> 2) + 4 * (lane >> 5);
      const float v = (acc[reg] + scratch[cf * 1024 + reg * 64 + lane]) / l_lds[row];
      out[(size_t)(i0 + row) * F + col] = eluf(v);
    }
  }
}

// ---------------------------------------------------------------------------
// Layer-2 fused attention. F=64, BR=32, 1024 thr (16 waves), BC=64 k-tiles.
// Wave w: rb = w&1 (16-row frag), cf = (w>>1)&3 (16-col frag), ks = w>>3.
// mfma_f32_16x16x32_bf16 over the wave's 32-k half; k-halves summed via LDS.
// ---------------------------------------------------------------------------
__global__ __launch_bounds__(1024, 4) void attn2_kernel(
    const float* __restrict__ Mm, const uint* __restrict__ Bm,
    const float* __restrict__ sv, const float* __restrict__ nv,
    const unsigned short* __restrict__ Th, const unsigned short* __restrict__ Tl,
    float* __restrict__ out) {
  constexpr int F = 64, BR = 32, NT = NN / 64;
  __shared__ __align__(16) uint Pa[2][2][1024];
  __shared__ __align__(16) float nvs[NN];
  __shared__ float l_lds[BR];

  const int t = threadIdx.x;
  const int lane = t & 63;
  const int w = t >> 6;
  const int rb = w & 1;
  const int cf = (w >> 1) & 3;
  const int ks = w >> 3;
  const int r = t >> 5;
  const int p2 = t & 31;
  const int i0 = blockIdx.x * BR;

  for (int i = t; i < NN / 4; i += 1024)
    reinterpret_cast<float4*>(nvs)[i] = reinterpret_cast<const float4*>(nv)[i];

  const float svr = sv[i0 + r];
  const size_t mrow = (size_t)(i0 + r) * NN;
  const uint* mkrow = Bm + (size_t)(i0 + r) * (NN / 32);
  const int col = cf * 16 + (lane & 15);
  const size_t bo2 = ((size_t)(lane >> 4) * F + col) * 8;
  const int pidx = ((p2 >> 2) * 32 + r) * 4 + (p2 & 3);
  const int aidx = ((ks * 4 + (lane >> 4)) * 32 + rb * 16 + (lane & 15)) * 4;

  float2 M_e = *reinterpret_cast<const float2*>(&Mm[mrow + 2 * p2]);
  float2 M_o = *reinterpret_cast<const float2*>(&Mm[mrow + 64 + 2 * p2]);
  uint mk_e = mkrow[0 + (p2 >> 4)];
  uint mk_o = mkrow[2 + (p2 >> 4)];
  const size_t tb0 = (size_t)ks * 2048;
  bf16x8 bh_e = *reinterpret_cast<const bf16x8*>(Th + tb0 + bo2);
  bf16x8 bl_e = *reinterpret_cast<const bf16x8*>(Tl + tb0 + bo2);
  bf16x8 bh_o, bl_o;

  float rsum = 0.f;
  f32x4 acc = {0.f, 0.f, 0.f, 0.f};

  __syncthreads();   // nvs staged

  float2 nv_e = *reinterpret_cast<const float2*>(&nvs[2 * p2]);
  float2 nv_o = *reinterpret_cast<const float2*>(&nvs[64 + 2 * p2]);

#define STEP2(TJ, MC, MKC, NVC, BHC, BLC, BHN, BLN)                               \
  {                                                                               \
    const int t_j = (TJ);                                                         \
    const int jb = (t_j + 1 < NT) ? t_j + 1 : 0;                                  \
    const size_t tb = (size_t)(2 * jb + ks) * 2048;                               \
    BHN = *reinterpret_cast<const bf16x8*>(Th + tb + bo2);                        \
    BLN = *reinterpret_cast<const bf16x8*>(Tl + tb + bo2);                        \
    float e0 = (svr + NVC.x) * MC.x; e0 = fmaxf(e0, 0.2f * e0); e0 = fminf(e0, 70.f); \
    float e1 = (svr + NVC.y) * MC.y; e1 = fmaxf(e1, 0.2f * e1); e1 = fminf(e1, 70.f); \
    const float p0 = ((MKC >> (2 * (p2 & 15))) & 1u) ? __expf(e0) : 0.f;          \
    const float p1 = ((MKC >> (2 * (p2 & 15) + 1)) & 1u) ? __expf(e1) : 0.f;      \
    rsum += p0 + p1;                                                              \
    const int jm = (t_j + 2 < NT) ? t_j + 2 : 0;                                  \
    MC = *reinterpret_cast<const float2*>(&Mm[mrow + (size_t)jm * 64 + 2 * p2]);  \
    MKC = mkrow[jm * 2 + (p2 >> 4)];                                              \
    NVC = *reinterpret_cast<const float2*>(&nvs[jm * 64 + 2 * p2]);               \
    const unsigned short h0 = bf16_hi(p0), h1 = bf16_hi(p1);                      \
    const uint hw = (uint)h0 | ((uint)h1 << 16);                                  \
    const uint lw = (uint)bf16_hi(p0 - bf16_tof(h0)) |                            \
                    ((uint)bf16_hi(p1 - bf16_tof(h1)) << 16);                     \
    Pa[t_j & 1][0][pidx] = hw;                                                    \
    Pa[t_j & 1][1][pidx] = lw;                                                    \
    lds_barrier();                                                                \
    const bf16x8 ah = *reinterpret_cast<const bf16x8*>(&Pa[t_j & 1][0][aidx]);    \
    const bf16x8 al = *reinterpret_cast<const bf16x8*>(&Pa[t_j & 1][1][aidx]);    \
    acc = __builtin_amdgcn_mfma_f32_16x16x32_bf16(al, BHC, acc, 0, 0, 0);         \
    acc = __builtin_amdgcn_mfma_f32_16x16x32_bf16(ah, BLC, acc, 0, 0, 0);         \
    acc = __builtin_amdgcn_mfma_f32_16x16x32_bf16(ah, BHC, acc, 0, 0, 0);         \
  }

  for (int tj = 0; tj < NT; tj += 2) {
    STEP2(tj,     M_e, mk_e, nv_e, bh_e, bl_e, bh_o, bl_o)
    STEP2(tj + 1, M_o, mk_o, nv_o, bh_o, bl_o, bh_e, bl_e)
  }
#undef STEP2

  #pragma unroll
  for (int off = 1; off < 32; off <<= 1) rsum += __shfl_xor(rsum, off);
  if (p2 == 0) l_lds[r] = rsum;
  __syncthreads();

  // k-half reduction through LDS scratch (reuse nvs: 8 * 256 floats)
  float* scratch = nvs;
  if (ks == 1) {
    #pragma unroll
    for (int reg = 0; reg < 4; ++reg) scratch[(w & 7) * 256 + reg * 64 + lane] = acc[reg];
  }
  __syncthreads();
  if (ks == 0) {
    #pragma unroll
    for (int reg = 0; reg < 4; ++reg) {
      const int row = rb * 16 + (lane >> 4) * 4 + reg;
      const float v = (acc[reg] + scratch[w * 256 + reg * 64 + lane]) / l_lds[row];
      out[(size_t)(i0 + row) * F + col] = eluf(v);
    }
  }
}

// ---------------------------------------------------------------------------
extern "C" void kernel_launch(void* const* d_in, const int* in_sizes, int n_in,
                              void* d_out, int out_size, void* d_ws, size_t ws_size,
                              hipStream_t stream) {
  const float* x   = (const float*)d_in[0];
  const int*   adj = (const int*)  d_in[1];
  const float* Mm  = (const float*)d_in[2];
  const float* W0  = (const float*)d_in[3];
  const float* as0 = (const float*)d_in[4];
  const float* an0 = (const float*)d_in[5];
  const float* W1  = (const float*)d_in[6];
  const float* as1 = (const float*)d_in[7];
  const float* an1 = (const float*)d_in[8];
  float* out = (float*)d_out;

  char* ws = (char*)d_ws;
  const size_t MB = 1048576;
  float* h0  = (float*)(ws);                              // 8 MB (dead after split1)
  uint*  Bm  = (uint*) (ws);                              // 8 MB (written after split1)
  float* x1  = (float*)(ws + 8 * MB);                     // 8 MB
  float* h1  = (float*)(ws + 16 * MB);                    // 2 MB
  unsigned short* Th0 = (unsigned short*)(ws + 18 * MB);  // 4 MB
  unsigned short* Tl0 = (unsigned short*)(ws + 22 * MB);  // 4 MB
  unsigned short* Th1 = (unsigned short*)(ws + 26 * MB);  // 1 MB
  unsigned short* Tl1 = (unsigned short*)(ws + 27 * MB);  // 1 MB
  float* s0 = (float*)(ws + 28 * MB);
  float* n0 = s0 + NN;
  float* s1 = n0 + NN;
  float* n1 = s1 + NN;

  // ---- layer 1 ----
  gemm_kernel<512, 256><<<dim3(128, 4), dim3(256), 0, stream>>>(x, W0, h0);
  sn_kernel<256><<<dim3(2048), dim3(256), 0, stream>>>(h0, as0, an0, s0, n0);
  split_kernel<256><<<dim3(256), dim3(256), 0, stream>>>(h0, Th0, Tl0);
  mask_kernel<<<dim3(65536), dim3(256), 0, stream>>>(adj, Bm);   // h0 now dead
  attn1_kernel<<<dim3(256), dim3(1024), 0, stream>>>(Mm, Bm, s0, n0, Th0, Tl0, x1);
  // ---- layer 2 ----
  gemm_kernel<256, 64><<<dim3(128, 1), dim3(256), 0, stream>>>(x1, W1, h1);
  sn_kernel<64><<<dim3(2048), dim3(256), 0, stream>>>(h1, as1, an1, s1, n1);
  split_kernel<64><<<dim3(256), dim3(256), 0, stream>>>(h1, Th1, Tl1);
  attn2_kernel<<<dim3(256), dim3(1024), 0, stream>>>(Mm, Bm, s1, n1, Th1, Tl1, out);
}